// Round 1
// baseline (2621.879 us; speedup 1.0000x reference)
//
#include <hip/hip_runtime.h>
#include <math.h>

// Problem constants (from reference setup_inputs)
#define B_  16
#define F_  8
#define C_  8          // multivector components
#define G_  32
#define G3_ 32768      // G^3
#define P_  4
#define N_  (B_*F_*C_*G3_)   // 33554432 floats = 128 MiB
#define SF_ (C_*G3_)         // field stride   262144
#define SB_ (F_*SF_)         // batch stride  2097152
#define WEXP_SZ (P_*F_*8*27*8)  // 55296

// Cl(3,0) Cayley: for each (i,j) exactly one k with sign s: W_eff[i,j,c] = s*w[c,k]
__device__ __constant__ int c_k[8][8] = {
  {0,1,2,3,4,5,6,7},
  {1,0,4,5,2,3,7,6},
  {2,4,0,6,1,7,3,5},
  {3,5,6,0,7,1,2,4},
  {4,2,1,7,0,6,5,3},
  {5,3,7,1,6,0,4,2},
  {6,7,3,2,5,4,0,1},
  {7,6,5,4,3,2,1,0}};
__device__ __constant__ float c_s[8][8] = {
  { 1, 1, 1, 1,-1,-1,-1,-1},
  { 1, 1, 1, 1,-1,-1,-1,-1},
  { 1,-1, 1, 1, 1, 1,-1, 1},
  { 1,-1,-1, 1,-1, 1, 1,-1},
  { 1,-1, 1, 1, 1, 1,-1, 1},
  { 1,-1,-1, 1,-1, 1, 1,-1},
  { 1, 1,-1, 1, 1,-1, 1, 1},
  { 1, 1,-1, 1, 1,-1, 1, 1}};

// ---------------------------------------------------------------------------
// prep: expand Cayley weights  W[p][f][j][dz][dy][dx][i]  (24 contig per j,dz,dy)
//       and softmax mix logits  mix[p][g][f]
__global__ void prep_kernel(const float* __restrict__ all_weights,   // [F][P][27][8]
                            const float* __restrict__ mix_logits,    // [P][F][F]
                            float* __restrict__ Wexp,
                            float* __restrict__ mix) {
  int tid = threadIdx.x;
  for (int idx = tid; idx < WEXP_SZ; idx += blockDim.x) {
    int i = idx & 7;
    int c = (idx >> 3) % 27;
    int j = (idx / (8*27)) & 7;
    int f = (idx / (8*27*8)) % F_;
    int p =  idx / (8*27*8*F_);
    int k = c_k[i][j];
    float s = c_s[i][j];
    Wexp[idx] = s * all_weights[((f*P_ + p)*27 + c)*8 + k];
  }
  if (tid < P_*F_) {
    int p = tid / F_, g = tid % F_;
    const float* row = &mix_logits[(p*F_ + g)*F_];
    float m = row[0];
    for (int f = 1; f < F_; ++f) m = fmaxf(m, row[f]);
    float e[F_]; float sum = 0.f;
    for (int f = 0; f < F_; ++f) { e[f] = expf(row[f] - m); sum += e[f]; }
    float inv = 1.f / sum;
    for (int f = 0; f < F_; ++f) mix[(p*F_ + g)*F_ + f] = e[f] * inv;
  }
}

// ---------------------------------------------------------------------------
// conv + tanh.  Causal 3^3 conv: out(z,y,x) uses in(z-2..z, y-2..y, x-2..x).
// Tile: zt=2, yt=16, full x.  128 threads; each thread: 8 comps x 8-x strip.
// Stage 4 of 8 input comps at a time -> LDS 4*4*18*36*4B = 40.5KiB + 6.75KiB w.
#define ZT 2
#define YT 16
#define CONV_THREADS 128

__global__ void conv_kernel(const float* __restrict__ xsrc,
                            float* __restrict__ y,
                            const float* __restrict__ Wexp,
                            const float* __restrict__ biases,   // [F][P][8]
                            int p) {
  __shared__ __align__(16) float tile[4][ZT+2][YT+2][36];
  __shared__ __align__(16) float wl[8*27*8];   // 1728 per (p,f)

  int bid = blockIdx.x;
  int yt = bid & 1;
  int zt = (bid >> 1) & 15;
  int f  = (bid >> 5) & 7;
  int b  =  bid >> 8;
  int z0 = zt * ZT, y0 = yt * YT;
  int tid = threadIdx.x;

  const float* wsrc = Wexp + (p*F_ + f) * (8*27*8);
  for (int i2 = tid; i2 < 8*27*8; i2 += CONV_THREADS) wl[i2] = wsrc[i2];

  float acc[8][8];
  #pragma unroll
  for (int i = 0; i < 8; ++i)
    #pragma unroll
    for (int xo = 0; xo < 8; ++xo) acc[i][xo] = 0.f;

  int row = tid >> 2;        // 0..31  (z,y) rows
  int t   = tid & 3;         // x-strip slot
  int zz  = row >> 4;        // 0..1
  int yy  = row & 15;        // 0..15
  int x0  = t * 8;

  const float* xb = xsrc + b*SB_ + f*SF_;

  for (int stg = 0; stg < 2; ++stg) {
    int jbase = stg * 4;
    __syncthreads();   // (iter0: after wl staging; iter1: protect tile reuse)
    // stage comps jbase..jbase+3 with causal halo, zero-fill OOB
    for (int idx = tid; idx < 4*(ZT+2)*(YT+2)*36; idx += CONV_THREADS) {
      int x  = idx % 36;
      int r  = idx / 36;
      int yyp = r % (YT+2);  r /= (YT+2);
      int zzp = r % (ZT+2);
      int cj  = r / (ZT+2);
      int gz = z0 + zzp - 2, gy = y0 + yyp - 2, gx = x - 2;
      float v = 0.f;
      if (gz >= 0 && gy >= 0 && gx >= 0 && gx < G_)
        v = xb[(jbase+cj)*G3_ + gz*(G_*G_) + gy*G_ + gx];
      tile[cj][zzp][yyp][x] = v;
    }
    __syncthreads();

    #pragma unroll 1
    for (int j = 0; j < 4; ++j) {
      int jj = jbase + j;
      #pragma unroll 1
      for (int dz = 0; dz < 3; ++dz) {
        #pragma unroll 1
        for (int dy = 0; dy < 3; ++dy) {
          const float* src = &tile[j][zz+dz][yy+dy][x0];
          float4 v0 = *(const float4*)(src);
          float4 v1 = *(const float4*)(src+4);
          float2 v2 = *(const float2*)(src+8);
          float in[10] = {v0.x,v0.y,v0.z,v0.w, v1.x,v1.y,v1.z,v1.w, v2.x,v2.y};
          const float* wp = &wl[(jj*27 + dz*9 + dy*3) * 8];   // [dx][i], 24 contig
          #pragma unroll
          for (int dx = 0; dx < 3; ++dx)
            #pragma unroll
            for (int i = 0; i < 8; ++i) {
              float w = wp[dx*8 + i];
              #pragma unroll
              for (int xo = 0; xo < 8; ++xo)
                acc[i][xo] = fmaf(w, in[xo+dx], acc[i][xo]);
            }
        }
      }
    }
  }

  float* yb = y + b*SB_ + f*SF_ + (z0+zz)*(G_*G_) + (y0+yy)*G_ + x0;
  #pragma unroll
  for (int i = 0; i < 8; ++i) {
    float bias = biases[(f*P_ + p)*8 + i];
    float o[8];
    #pragma unroll
    for (int xo = 0; xo < 8; ++xo) o[xo] = tanhf(acc[i][xo] + bias);
    float4 a0 = {o[0],o[1],o[2],o[3]};
    float4 a1 = {o[4],o[5],o[6],o[7]};
    *(float4*)(yb + i*G3_)     = a0;
    *(float4*)(yb + i*G3_ + 4) = a1;
  }
}

// ---------------------------------------------------------------------------
// cross-field mix + residual: X[b,g,i,s] = a*xb + (1-a)*sum_f mix[g,f]*Y[b,f,i,s]
__global__ void mix_kernel(const float* __restrict__ ybuf,
                           const float* __restrict__ xbsrc,
                           float* __restrict__ xdst,
                           const float* __restrict__ mix,
                           const float* __restrict__ pal,
                           int p) {
  int tid = blockIdx.x * blockDim.x + threadIdx.x;   // 1,048,576 total
  int s4 = tid & 8191;            // G3/4
  int i  = (tid >> 13) & 7;
  int b  =  tid >> 16;
  int base = b*SB_ + i*G3_ + s4*4;
  float a  = 1.f / (1.f + expf(-pal[p]));
  float na = 1.f - a;

  float mr[8][8];
  #pragma unroll
  for (int g = 0; g < 8; ++g)
    #pragma unroll
    for (int ff = 0; ff < 8; ++ff) mr[g][ff] = mix[(p*8 + g)*8 + ff];

  float4 yv[8];
  #pragma unroll
  for (int ff = 0; ff < 8; ++ff) yv[ff] = *(const float4*)(ybuf + base + ff*SF_);

  #pragma unroll
  for (int g = 0; g < 8; ++g) {
    float4 xb = *(const float4*)(xbsrc + base + g*SF_);
    float sx = 0.f, sy = 0.f, sz = 0.f, sw = 0.f;
    #pragma unroll
    for (int ff = 0; ff < 8; ++ff) {
      float m = mr[g][ff];
      sx = fmaf(m, yv[ff].x, sx);
      sy = fmaf(m, yv[ff].y, sy);
      sz = fmaf(m, yv[ff].z, sz);
      sw = fmaf(m, yv[ff].w, sw);
    }
    float4 o;
    o.x = a*xb.x + na*sx;  o.y = a*xb.y + na*sy;
    o.z = a*xb.z + na*sz;  o.w = a*xb.w + na*sw;
    *(float4*)(xdst + base + g*SF_) = o;
  }
}

// ---------------------------------------------------------------------------
// final gate: out = sig(gw*old+gb)*old + (1-sig)*x
__global__ void gate_kernel(const float* __restrict__ state,
                            const float* __restrict__ xfin,
                            const float* __restrict__ gw,
                            const float* __restrict__ gb,
                            float* __restrict__ out) {
  int tid = blockIdx.x * blockDim.x + threadIdx.x;   // N/4
  int flat = tid * 4;
  int fc = (flat >> 15) & 63;    // (f*8 + comp)
  float w = gw[fc], bb = gb[fc];
  float4 o4 = *(const float4*)(state + flat);
  float4 x4 = *(const float4*)(xfin + flat);
  float4 r;
  {
    float g = 1.f/(1.f+expf(-(w*o4.x+bb))); r.x = g*o4.x + (1.f-g)*x4.x;
  }
  {
    float g = 1.f/(1.f+expf(-(w*o4.y+bb))); r.y = g*o4.y + (1.f-g)*x4.y;
  }
  {
    float g = 1.f/(1.f+expf(-(w*o4.z+bb))); r.z = g*o4.z + (1.f-g)*x4.z;
  }
  {
    float g = 1.f/(1.f+expf(-(w*o4.w+bb))); r.w = g*o4.w + (1.f-g)*x4.w;
  }
  *(float4*)(out + flat) = r;
}

// ---------------------------------------------------------------------------
extern "C" void kernel_launch(void* const* d_in, const int* in_sizes, int n_in,
                              void* d_out, int out_size, void* d_ws, size_t ws_size,
                              hipStream_t stream) {
  (void)in_sizes; (void)n_in; (void)out_size; (void)ws_size;
  const float* state       = (const float*)d_in[0];
  const float* all_weights = (const float*)d_in[1];
  const float* all_biases  = (const float*)d_in[2];
  const float* mix_logits  = (const float*)d_in[3];
  const float* pal         = (const float*)d_in[4];
  const float* gw          = (const float*)d_in[5];
  const float* gb          = (const float*)d_in[6];
  float* out = (float*)d_out;

  // ws layout: X (N_) | Wexp (55296) | mix (256)   -> ~128.2 MiB needed
  float* X    = (float*)d_ws;
  float* Wexp = X + N_;
  float* mixb = Wexp + WEXP_SZ;
  float* Y    = out;   // d_out doubles as y scratch; overwritten by gate_kernel

  prep_kernel<<<1, 256, 0, stream>>>(all_weights, mix_logits, Wexp, mixb);

  for (int p = 0; p < P_; ++p) {
    const float* xcur = (p == 0) ? state : X;   // x_before / conv input
    conv_kernel<<<dim3(B_*F_*(G_/ZT)*(G_/YT)), dim3(CONV_THREADS), 0, stream>>>(
        xcur, Y, Wexp, all_biases, p);
    mix_kernel<<<dim3((B_*C_*(G3_/4))/256), dim3(256), 0, stream>>>(
        Y, xcur, X, mixb, pal, p);
  }

  gate_kernel<<<dim3(N_/4/256), dim3(256), 0, stream>>>(state, X, gw, gb, out);
}

// Round 2
// 1242.885 us; speedup vs baseline: 2.1095x; 2.1095x over previous
//
#include <hip/hip_runtime.h>
#include <math.h>

// Problem constants (from reference setup_inputs)
#define B_  16
#define F_  8
#define C_  8          // multivector components
#define G_  32
#define G3_ 32768      // G^3
#define P_  4
#define N_  (B_*F_*C_*G3_)   // 33554432 floats = 128 MiB
#define SF_ (C_*G3_)         // field stride   262144
#define SB_ (F_*SF_)         // batch stride  2097152
#define WEXP_SZ (P_*F_*8*27*8)  // 55296

// Cl(3,0) Cayley: for each (i,j) exactly one k with sign s: W_eff[i,j,c] = s*w[c,k]
__device__ __constant__ int c_k[8][8] = {
  {0,1,2,3,4,5,6,7},
  {1,0,4,5,2,3,7,6},
  {2,4,0,6,1,7,3,5},
  {3,5,6,0,7,1,2,4},
  {4,2,1,7,0,6,5,3},
  {5,3,7,1,6,0,4,2},
  {6,7,3,2,5,4,0,1},
  {7,6,5,4,3,2,1,0}};
__device__ __constant__ float c_s[8][8] = {
  { 1, 1, 1, 1,-1,-1,-1,-1},
  { 1, 1, 1, 1,-1,-1,-1,-1},
  { 1,-1, 1, 1, 1, 1,-1, 1},
  { 1,-1,-1, 1,-1, 1, 1,-1},
  { 1,-1, 1, 1, 1, 1,-1, 1},
  { 1,-1,-1, 1,-1, 1, 1,-1},
  { 1, 1,-1, 1, 1,-1, 1, 1},
  { 1, 1,-1, 1, 1,-1, 1, 1}};

__device__ __forceinline__ float fast_tanh(float v) {
  float e = __expf(2.f * v);
  return 1.f - 2.f / (e + 1.f);
}
__device__ __forceinline__ float fast_sig(float v) {
  return 1.f / (1.f + __expf(-v));
}

// ---------------------------------------------------------------------------
// prep: expand Cayley weights  W[p][f][j][dz][dy][dx][i]  (24 contig per j,dz,dy)
//       and softmax mix logits  mix[p][g][f]
__global__ void prep_kernel(const float* __restrict__ all_weights,   // [F][P][27][8]
                            const float* __restrict__ mix_logits,    // [P][F][F]
                            float* __restrict__ Wexp,
                            float* __restrict__ mix) {
  int tid = threadIdx.x;
  for (int idx = tid; idx < WEXP_SZ; idx += blockDim.x) {
    int i = idx & 7;
    int c = (idx >> 3) % 27;
    int j = (idx / (8*27)) & 7;
    int f = (idx / (8*27*8)) % F_;
    int p =  idx / (8*27*8*F_);
    int k = c_k[i][j];
    float s = c_s[i][j];
    Wexp[idx] = s * all_weights[((f*P_ + p)*27 + c)*8 + k];
  }
  if (tid < P_*F_) {
    int p = tid / F_, g = tid % F_;
    const float* row = &mix_logits[(p*F_ + g)*F_];
    float m = row[0];
    for (int f = 1; f < F_; ++f) m = fmaxf(m, row[f]);
    float e[F_]; float sum = 0.f;
    for (int f = 0; f < F_; ++f) { e[f] = __expf(row[f] - m); sum += e[f]; }
    float inv = 1.f / sum;
    for (int f = 0; f < F_; ++f) mix[(p*F_ + g)*F_ + f] = e[f] * inv;
  }
}

// ---------------------------------------------------------------------------
// conv + tanh.  Causal 3^3 conv: out(z,y,x) uses in(z-2..z, y-2..y, x-2..x).
// Tile: zt=2, yt=16, full x.  256 threads; each thread: 8 comps x 4-x strip.
// Stage 2 of 8 input comps at a time -> LDS = 2*4*18*36*4B = 20.25 KiB.
// Weights read through wave-uniform global pointers -> SGPR s_load path.
#define ZT 2
#define YT 16
#define CONV_THREADS 256
#define SELEMS (2*(ZT+2)*(YT+2)*36)   // 5184 per stage

__global__ __launch_bounds__(CONV_THREADS, 6)
void conv_kernel(const float* __restrict__ xsrc,
                 float* __restrict__ y,
                 const float* __restrict__ Wexp,
                 const float* __restrict__ biases,   // [F][P][8]
                 int p) {
  __shared__ __align__(16) float tile[2][ZT+2][YT+2][36];

  int bid = blockIdx.x;
  int yt = bid & 1;
  int zt = (bid >> 1) & 15;
  int f  = (bid >> 5) & 7;
  int b  =  bid >> 8;
  int z0 = zt * ZT, y0 = yt * YT;
  int tid = threadIdx.x;

  float acc[8][4];
  #pragma unroll
  for (int i = 0; i < 8; ++i)
    #pragma unroll
    for (int xo = 0; xo < 4; ++xo) acc[i][xo] = 0.f;

  int t   = tid & 7;         // x-strip slot (4 wide)
  int row = tid >> 3;        // 0..31  (z,y) rows
  int zz  = row >> 4;        // 0..1
  int yy  = row & 15;        // 0..15
  int x0  = t * 4;

  const float* xb = xsrc + b*SB_ + f*SF_;
  const float* wf = Wexp + (p*F_ + f) * (8*27*8);   // wave-uniform

  for (int stg = 0; stg < 4; ++stg) {
    int jbase = stg * 2;
    if (stg) __syncthreads();   // protect tile before overwrite
    // stage comps jbase..jbase+1 with causal halo, zero-fill OOB
    for (int idx = tid; idx < SELEMS; idx += CONV_THREADS) {
      int x  = idx % 36;
      int r  = idx / 36;
      int yyp = r % (YT+2);  r /= (YT+2);
      int zzp = r % (ZT+2);
      int cj  = r / (ZT+2);
      int gz = z0 + zzp - 2, gy = y0 + yyp - 2, gx = x - 2;
      float v = 0.f;
      if (gz >= 0 && gy >= 0 && gx >= 0 && gx < G_)
        v = xb[(jbase+cj)*G3_ + gz*(G_*G_) + gy*G_ + gx];
      tile[cj][zzp][yyp][x] = v;
    }
    __syncthreads();

    #pragma unroll 1
    for (int j = 0; j < 2; ++j) {
      const float* wj = wf + (jbase + j) * (27*8);   // wave-uniform
      #pragma unroll 1
      for (int dz = 0; dz < 3; ++dz) {
        #pragma unroll 1
        for (int dy = 0; dy < 3; ++dy) {
          const float* src = &tile[j][zz+dz][yy+dy][x0];
          float4 v0 = *(const float4*)(src);
          float2 v1 = *(const float2*)(src+4);
          float in[6] = {v0.x,v0.y,v0.z,v0.w, v1.x,v1.y};
          const float* wp = wj + (dz*9 + dy*3) * 8;   // [dx][i], 24 contig, uniform
          #pragma unroll
          for (int dx = 0; dx < 3; ++dx)
            #pragma unroll
            for (int i = 0; i < 8; ++i) {
              float w = wp[dx*8 + i];
              #pragma unroll
              for (int xo = 0; xo < 4; ++xo)
                acc[i][xo] = fmaf(w, in[xo+dx], acc[i][xo]);
            }
        }
      }
    }
  }

  float* yb = y + b*SB_ + f*SF_ + (z0+zz)*(G_*G_) + (y0+yy)*G_ + x0;
  #pragma unroll
  for (int i = 0; i < 8; ++i) {
    float bias = biases[(f*P_ + p)*8 + i];
    float4 a0;
    a0.x = fast_tanh(acc[i][0] + bias);
    a0.y = fast_tanh(acc[i][1] + bias);
    a0.z = fast_tanh(acc[i][2] + bias);
    a0.w = fast_tanh(acc[i][3] + bias);
    *(float4*)(yb + i*G3_) = a0;
  }
}

// ---------------------------------------------------------------------------
// cross-field mix + residual: X[b,g,i,s] = a*xb + (1-a)*sum_f mix[g,f]*Y[b,f,i,s]
__global__ void mix_kernel(const float* __restrict__ ybuf,
                           const float* __restrict__ xbsrc,
                           float* __restrict__ xdst,
                           const float* __restrict__ mix,
                           const float* __restrict__ pal,
                           int p) {
  int tid = blockIdx.x * blockDim.x + threadIdx.x;   // 1,048,576 total
  int s4 = tid & 8191;            // G3/4
  int i  = (tid >> 13) & 7;
  int b  =  tid >> 16;
  int base = b*SB_ + i*G3_ + s4*4;
  float a  = fast_sig(pal[p]);
  float na = 1.f - a;

  float4 yv[8];
  #pragma unroll
  for (int ff = 0; ff < 8; ++ff) yv[ff] = *(const float4*)(ybuf + base + ff*SF_);

  #pragma unroll
  for (int g = 0; g < 8; ++g) {
    float4 xb = *(const float4*)(xbsrc + base + g*SF_);
    float sx = 0.f, sy = 0.f, sz = 0.f, sw = 0.f;
    #pragma unroll
    for (int ff = 0; ff < 8; ++ff) {
      float m = mix[(p*8 + g)*8 + ff];
      sx = fmaf(m, yv[ff].x, sx);
      sy = fmaf(m, yv[ff].y, sy);
      sz = fmaf(m, yv[ff].z, sz);
      sw = fmaf(m, yv[ff].w, sw);
    }
    float4 o;
    o.x = a*xb.x + na*sx;  o.y = a*xb.y + na*sy;
    o.z = a*xb.z + na*sz;  o.w = a*xb.w + na*sw;
    *(float4*)(xdst + base + g*SF_) = o;
  }
}

// ---------------------------------------------------------------------------
// final pass mix fused with the output gate:
//   xfin = a*xb + (1-a)*(M y);  gate = sig(gw*old+gb);  out = gate*old + (1-gate)*xfin
__global__ void mixgate_kernel(const float* __restrict__ ybuf,
                               const float* __restrict__ xbsrc,
                               const float* __restrict__ state,
                               float* __restrict__ out,
                               const float* __restrict__ mix,
                               const float* __restrict__ pal,
                               const float* __restrict__ gw,
                               const float* __restrict__ gb,
                               int p) {
  int tid = blockIdx.x * blockDim.x + threadIdx.x;
  int s4 = tid & 8191;
  int i  = (tid >> 13) & 7;
  int b  =  tid >> 16;
  int base = b*SB_ + i*G3_ + s4*4;
  float a  = fast_sig(pal[p]);
  float na = 1.f - a;

  float4 yv[8];
  #pragma unroll
  for (int ff = 0; ff < 8; ++ff) yv[ff] = *(const float4*)(ybuf + base + ff*SF_);

  #pragma unroll
  for (int g = 0; g < 8; ++g) {
    float4 xb = *(const float4*)(xbsrc + base + g*SF_);
    float4 st = *(const float4*)(state + base + g*SF_);
    float sx = 0.f, sy = 0.f, sz = 0.f, sw = 0.f;
    #pragma unroll
    for (int ff = 0; ff < 8; ++ff) {
      float m = mix[(p*8 + g)*8 + ff];
      sx = fmaf(m, yv[ff].x, sx);
      sy = fmaf(m, yv[ff].y, sy);
      sz = fmaf(m, yv[ff].z, sz);
      sw = fmaf(m, yv[ff].w, sw);
    }
    float xfx = a*xb.x + na*sx, xfy = a*xb.y + na*sy;
    float xfz = a*xb.z + na*sz, xfw = a*xb.w + na*sw;
    float w = gw[g*8 + i], bb = gb[g*8 + i];
    float4 r;
    { float gt = fast_sig(w*st.x + bb); r.x = gt*st.x + (1.f-gt)*xfx; }
    { float gt = fast_sig(w*st.y + bb); r.y = gt*st.y + (1.f-gt)*xfy; }
    { float gt = fast_sig(w*st.z + bb); r.z = gt*st.z + (1.f-gt)*xfz; }
    { float gt = fast_sig(w*st.w + bb); r.w = gt*st.w + (1.f-gt)*xfw; }
    *(float4*)(out + base + g*SF_) = r;
  }
}

// ---------------------------------------------------------------------------
extern "C" void kernel_launch(void* const* d_in, const int* in_sizes, int n_in,
                              void* d_out, int out_size, void* d_ws, size_t ws_size,
                              hipStream_t stream) {
  (void)in_sizes; (void)n_in; (void)out_size; (void)ws_size;
  const float* state       = (const float*)d_in[0];
  const float* all_weights = (const float*)d_in[1];
  const float* all_biases  = (const float*)d_in[2];
  const float* mix_logits  = (const float*)d_in[3];
  const float* pal         = (const float*)d_in[4];
  const float* gw          = (const float*)d_in[5];
  const float* gb          = (const float*)d_in[6];
  float* out = (float*)d_out;

  // ws layout: X (N_) | Wexp (55296) | mix (256)   -> ~128.2 MiB needed
  float* X    = (float*)d_ws;
  float* Wexp = X + N_;
  float* mixb = Wexp + WEXP_SZ;
  float* Y    = out;   // d_out doubles as y scratch; overwritten by mixgate

  prep_kernel<<<1, 256, 0, stream>>>(all_weights, mix_logits, Wexp, mixb);

  for (int p = 0; p < P_; ++p) {
    const float* xcur = (p == 0) ? state : X;   // x_before / conv input
    conv_kernel<<<dim3(B_*F_*(G_/ZT)*(G_/YT)), dim3(CONV_THREADS), 0, stream>>>(
        xcur, Y, Wexp, all_biases, p);
    if (p < P_ - 1) {
      mix_kernel<<<dim3((B_*C_*(G3_/4))/256), dim3(256), 0, stream>>>(
          Y, xcur, X, mixb, pal, p);
    } else {
      mixgate_kernel<<<dim3((B_*C_*(G3_/4))/256), dim3(256), 0, stream>>>(
          Y, X, state, out, mixb, pal, gw, gb, p);
    }
  }
}

// Round 3
// 1074.538 us; speedup vs baseline: 2.4400x; 1.1567x over previous
//
#include <hip/hip_runtime.h>
#include <math.h>

// Problem constants (from reference setup_inputs)
#define B_  16
#define F_  8
#define C_  8          // multivector components
#define G_  32
#define G3_ 32768      // G^3
#define P_  4
#define N_  (B_*F_*C_*G3_)   // 33554432 floats = 128 MiB
#define SF_ (C_*G3_)         // field stride   262144
#define SB_ (F_*SF_)         // batch stride  2097152
#define WEXP_SZ (P_*F_*8*27*8)  // 55296

// Cl(3,0) Cayley: for each (i,j) exactly one k with sign s: W_eff[i,j,c] = s*w[c,k]
__device__ __constant__ int c_k[8][8] = {
  {0,1,2,3,4,5,6,7},
  {1,0,4,5,2,3,7,6},
  {2,4,0,6,1,7,3,5},
  {3,5,6,0,7,1,2,4},
  {4,2,1,7,0,6,5,3},
  {5,3,7,1,6,0,4,2},
  {6,7,3,2,5,4,0,1},
  {7,6,5,4,3,2,1,0}};
__device__ __constant__ float c_s[8][8] = {
  { 1, 1, 1, 1,-1,-1,-1,-1},
  { 1, 1, 1, 1,-1,-1,-1,-1},
  { 1,-1, 1, 1, 1, 1,-1, 1},
  { 1,-1,-1, 1,-1, 1, 1,-1},
  { 1,-1, 1, 1, 1, 1,-1, 1},
  { 1,-1,-1, 1,-1, 1, 1,-1},
  { 1, 1,-1, 1, 1,-1, 1, 1},
  { 1, 1,-1, 1, 1,-1, 1, 1}};

__device__ __forceinline__ float fast_tanh(float v) {
  float e = __expf(2.f * v);
  return 1.f - 2.f / (e + 1.f);
}
__device__ __forceinline__ float fast_sig(float v) {
  return 1.f / (1.f + __expf(-v));
}

// ---------------------------------------------------------------------------
// prep: expand Cayley weights  W[p][f][j][dz][dy][dx][i]  (24 contig per j,dz,dy)
//       and softmax mix logits  mix[p][g][f]
__global__ void prep_kernel(const float* __restrict__ all_weights,   // [F][P][27][8]
                            const float* __restrict__ mix_logits,    // [P][F][F]
                            float* __restrict__ Wexp,
                            float* __restrict__ mix) {
  int tid = threadIdx.x;
  for (int idx = tid; idx < WEXP_SZ; idx += blockDim.x) {
    int i = idx & 7;
    int c = (idx >> 3) % 27;
    int j = (idx / (8*27)) & 7;
    int f = (idx / (8*27*8)) % F_;
    int p =  idx / (8*27*8*F_);
    int k = c_k[i][j];
    float s = c_s[i][j];
    Wexp[idx] = s * all_weights[((f*P_ + p)*27 + c)*8 + k];
  }
  if (tid < P_*F_) {
    int p = tid / F_, g = tid % F_;
    const float* row = &mix_logits[(p*F_ + g)*F_];
    float m = row[0];
    for (int f = 1; f < F_; ++f) m = fmaxf(m, row[f]);
    float e[F_]; float sum = 0.f;
    for (int f = 0; f < F_; ++f) { e[f] = __expf(row[f] - m); sum += e[f]; }
    float inv = 1.f / sum;
    for (int f = 0; f < F_; ++f) mix[(p*F_ + g)*F_ + f] = e[f] * inv;
  }
}

// ---------------------------------------------------------------------------
// conv + tanh.  Causal 3^3 conv: out(z,y,x) uses in(z-2..z, y-2..y, x-2..x).
// Tile: zt=2, yt=16, full x.  256 threads; each thread: 8 comps x 4-x strip.
// LDS row layout: [2 zero floats | 32 data floats], stride 34 -> 4-way max
// bank aliasing on b128 reads, reads 16B-aligned at offset x0.
// Stage 2 of 8 input comps at a time: 144 rows (2 comp * 4 z * 18 y).
#define ZT 2
#define YT 16
#define CONV_THREADS 256
#define TSTR 34                       // LDS row stride in floats
#define NROWS (2*(ZT+2)*(YT+2))       // 144 rows per stage

__global__ __launch_bounds__(CONV_THREADS, 8)
void conv_kernel(const float* __restrict__ xsrc,
                 float* __restrict__ y,
                 const float* __restrict__ Wexp,
                 const float* __restrict__ biases,   // [F][P][8]
                 int p) {
  __shared__ __align__(16) float tilef[NROWS * TSTR];   // 19584 B

  int bid = blockIdx.x;
  int yt = bid & 1;
  int zt = (bid >> 1) & 15;
  int f  = (bid >> 5) & 7;
  int b  =  bid >> 8;
  int z0 = zt * ZT, y0 = yt * YT;
  int tid = threadIdx.x;

  float acc[8][4];
  #pragma unroll
  for (int i = 0; i < 8; ++i)
    #pragma unroll
    for (int xo = 0; xo < 4; ++xo) acc[i][xo] = 0.f;

  int t   = tid & 7;         // x-strip slot (4 wide)
  int row = tid >> 3;        // 0..31  (z,y) rows
  int zz  = row >> 4;        // 0..1
  int yy  = row & 15;        // 0..15
  int x0  = t * 4;

  const float* xb = xsrc + b*SB_ + f*SF_;
  const float* wf = Wexp + (p*F_ + f) * (8*27*8);   // wave-uniform

  // zero the 2-float x-halo columns once; never overwritten (data x>=2)
  for (int idx = tid; idx < NROWS*2; idx += CONV_THREADS)
    tilef[(idx >> 1) * TSTR + (idx & 1)] = 0.f;

  for (int stg = 0; stg < 4; ++stg) {
    int jbase = stg * 2;
    __syncthreads();   // protect tile reads of prev stage (& zero-init on stg 0)
    // stage comps jbase..jbase+1: 144 rows x 8 float4 slots, coalesced
    for (int idx = tid; idx < NROWS*8; idx += CONV_THREADS) {
      int s  = idx & 7;
      int r  = idx >> 3;             // 0..143
      int cj = (r >= 72) ? 1 : 0;
      int rr = r - cj * 72;
      int z  = rr / 18;              // 0..3 (magic-mul)
      int yr = rr - z * 18;          // 0..17
      int gz = z0 + z - 2, gy = y0 + yr - 2;
      float4 v = make_float4(0.f, 0.f, 0.f, 0.f);
      if (gz >= 0 && gy >= 0)
        v = *(const float4*)(xb + (jbase+cj)*G3_ + (gz << 10) + (gy << 5) + (s << 2));
      int base = r * TSTR + 2 + (s << 2);
      *(float2*)(tilef + base)     = make_float2(v.x, v.y);
      *(float2*)(tilef + base + 2) = make_float2(v.z, v.w);
    }
    __syncthreads();

    #pragma unroll 1
    for (int j = 0; j < 2; ++j) {
      const float* wj = wf + (jbase + j) * (27*8);   // wave-uniform
      #pragma unroll 1
      for (int dz = 0; dz < 3; ++dz) {
        #pragma unroll 1
        for (int dy = 0; dy < 3; ++dy) {
          const float* src = tilef + ((j*4 + zz + dz)*18 + (yy + dy)) * TSTR + x0;
          float4 v0 = *(const float4*)(src);
          float2 v1 = *(const float2*)(src + 4);
          float in[6] = {v0.x, v0.y, v0.z, v0.w, v1.x, v1.y};
          const float* wp = wj + (dz*9 + dy*3) * 8;   // [dx][i], 24 contig, uniform
          #pragma unroll
          for (int dx = 0; dx < 3; ++dx)
            #pragma unroll
            for (int i = 0; i < 8; ++i) {
              float w = wp[dx*8 + i];
              #pragma unroll
              for (int xo = 0; xo < 4; ++xo)
                acc[i][xo] = fmaf(w, in[xo+dx], acc[i][xo]);
            }
        }
      }
    }
  }

  float* yb = y + b*SB_ + f*SF_ + (z0+zz)*(G_*G_) + (y0+yy)*G_ + x0;
  #pragma unroll
  for (int i = 0; i < 8; ++i) {
    float bias = biases[(f*P_ + p)*8 + i];
    float4 a0;
    a0.x = fast_tanh(acc[i][0] + bias);
    a0.y = fast_tanh(acc[i][1] + bias);
    a0.z = fast_tanh(acc[i][2] + bias);
    a0.w = fast_tanh(acc[i][3] + bias);
    *(float4*)(yb + i*G3_) = a0;
  }
}

// ---------------------------------------------------------------------------
// cross-field mix + residual: X[b,g,i,s] = a*xb + (1-a)*sum_f mix[g,f]*Y[b,f,i,s]
__global__ void mix_kernel(const float* __restrict__ ybuf,
                           const float* __restrict__ xbsrc,
                           float* __restrict__ xdst,
                           const float* __restrict__ mix,
                           const float* __restrict__ pal,
                           int p) {
  int tid = blockIdx.x * blockDim.x + threadIdx.x;   // 1,048,576 total
  int s4 = tid & 8191;            // G3/4
  int i  = (tid >> 13) & 7;
  int b  =  tid >> 16;
  int base = b*SB_ + i*G3_ + s4*4;
  float a  = fast_sig(pal[p]);
  float na = 1.f - a;

  float4 yv[8];
  #pragma unroll
  for (int ff = 0; ff < 8; ++ff) yv[ff] = *(const float4*)(ybuf + base + ff*SF_);

  #pragma unroll
  for (int g = 0; g < 8; ++g) {
    float4 xb = *(const float4*)(xbsrc + base + g*SF_);
    float sx = 0.f, sy = 0.f, sz = 0.f, sw = 0.f;
    #pragma unroll
    for (int ff = 0; ff < 8; ++ff) {
      float m = mix[(p*8 + g)*8 + ff];
      sx = fmaf(m, yv[ff].x, sx);
      sy = fmaf(m, yv[ff].y, sy);
      sz = fmaf(m, yv[ff].z, sz);
      sw = fmaf(m, yv[ff].w, sw);
    }
    float4 o;
    o.x = a*xb.x + na*sx;  o.y = a*xb.y + na*sy;
    o.z = a*xb.z + na*sz;  o.w = a*xb.w + na*sw;
    *(float4*)(xdst + base + g*SF_) = o;
  }
}

// ---------------------------------------------------------------------------
// final pass mix fused with the output gate:
//   xfin = a*xb + (1-a)*(M y);  gate = sig(gw*old+gb);  out = gate*old + (1-gate)*xfin
__global__ void mixgate_kernel(const float* __restrict__ ybuf,
                               const float* __restrict__ xbsrc,
                               const float* __restrict__ state,
                               float* __restrict__ out,
                               const float* __restrict__ mix,
                               const float* __restrict__ pal,
                               const float* __restrict__ gw,
                               const float* __restrict__ gb,
                               int p) {
  int tid = blockIdx.x * blockDim.x + threadIdx.x;
  int s4 = tid & 8191;
  int i  = (tid >> 13) & 7;
  int b  =  tid >> 16;
  int base = b*SB_ + i*G3_ + s4*4;
  float a  = fast_sig(pal[p]);
  float na = 1.f - a;

  float4 yv[8];
  #pragma unroll
  for (int ff = 0; ff < 8; ++ff) yv[ff] = *(const float4*)(ybuf + base + ff*SF_);

  #pragma unroll
  for (int g = 0; g < 8; ++g) {
    float4 xb = *(const float4*)(xbsrc + base + g*SF_);
    float4 st = *(const float4*)(state + base + g*SF_);
    float sx = 0.f, sy = 0.f, sz = 0.f, sw = 0.f;
    #pragma unroll
    for (int ff = 0; ff < 8; ++ff) {
      float m = mix[(p*8 + g)*8 + ff];
      sx = fmaf(m, yv[ff].x, sx);
      sy = fmaf(m, yv[ff].y, sy);
      sz = fmaf(m, yv[ff].z, sz);
      sw = fmaf(m, yv[ff].w, sw);
    }
    float xfx = a*xb.x + na*sx, xfy = a*xb.y + na*sy;
    float xfz = a*xb.z + na*sz, xfw = a*xb.w + na*sw;
    float w = gw[g*8 + i], bb = gb[g*8 + i];
    float4 r;
    { float gt = fast_sig(w*st.x + bb); r.x = gt*st.x + (1.f-gt)*xfx; }
    { float gt = fast_sig(w*st.y + bb); r.y = gt*st.y + (1.f-gt)*xfy; }
    { float gt = fast_sig(w*st.z + bb); r.z = gt*st.z + (1.f-gt)*xfz; }
    { float gt = fast_sig(w*st.w + bb); r.w = gt*st.w + (1.f-gt)*xfw; }
    *(float4*)(out + base + g*SF_) = r;
  }
}

// ---------------------------------------------------------------------------
extern "C" void kernel_launch(void* const* d_in, const int* in_sizes, int n_in,
                              void* d_out, int out_size, void* d_ws, size_t ws_size,
                              hipStream_t stream) {
  (void)in_sizes; (void)n_in; (void)out_size; (void)ws_size;
  const float* state       = (const float*)d_in[0];
  const float* all_weights = (const float*)d_in[1];
  const float* all_biases  = (const float*)d_in[2];
  const float* mix_logits  = (const float*)d_in[3];
  const float* pal         = (const float*)d_in[4];
  const float* gw          = (const float*)d_in[5];
  const float* gb          = (const float*)d_in[6];
  float* out = (float*)d_out;

  // ws layout: X (N_) | Wexp (55296) | mix (256)   -> ~128.2 MiB needed
  float* X    = (float*)d_ws;
  float* Wexp = X + N_;
  float* mixb = Wexp + WEXP_SZ;
  float* Y    = out;   // d_out doubles as y scratch; overwritten by mixgate

  prep_kernel<<<1, 256, 0, stream>>>(all_weights, mix_logits, Wexp, mixb);

  for (int p = 0; p < P_; ++p) {
    const float* xcur = (p == 0) ? state : X;   // x_before / conv input
    conv_kernel<<<dim3(B_*F_*(G_/ZT)*(G_/YT)), dim3(CONV_THREADS), 0, stream>>>(
        xcur, Y, Wexp, all_biases, p);
    if (p < P_ - 1) {
      mix_kernel<<<dim3((B_*C_*(G3_/4))/256), dim3(256), 0, stream>>>(
          Y, xcur, X, mixb, pal, p);
    } else {
      mixgate_kernel<<<dim3((B_*C_*(G3_/4))/256), dim3(256), 0, stream>>>(
          Y, X, state, out, mixb, pal, gw, gb, p);
    }
  }
}

// Round 4
// 690.964 us; speedup vs baseline: 3.7945x; 1.5551x over previous
//
#include <hip/hip_runtime.h>
#include <math.h>

// Problem constants (from reference setup_inputs)
#define B_  16
#define F_  8
#define C_  8          // multivector components
#define G_  32
#define G3_ 32768      // G^3
#define P_  4
#define N_  (B_*F_*C_*G3_)   // 33554432 floats = 128 MiB
#define SF_ (C_*G3_)         // field stride   262144
#define SB_ (F_*SF_)         // batch stride  2097152
#define APACK_SZ (P_*F_*9*64*8)  // 147456 ushort (bf16 A fragments)

typedef __attribute__((ext_vector_type(8))) short short8v;
typedef __attribute__((ext_vector_type(4))) float f32x4;

// Cl(3,0) Cayley: for each (i,j) exactly one k with sign s: W_eff[i,j,c] = s*w[c,k]
__device__ __constant__ int c_k[8][8] = {
  {0,1,2,3,4,5,6,7},
  {1,0,4,5,2,3,7,6},
  {2,4,0,6,1,7,3,5},
  {3,5,6,0,7,1,2,4},
  {4,2,1,7,0,6,5,3},
  {5,3,7,1,6,0,4,2},
  {6,7,3,2,5,4,0,1},
  {7,6,5,4,3,2,1,0}};
__device__ __constant__ float c_s[8][8] = {
  { 1, 1, 1, 1,-1,-1,-1,-1},
  { 1, 1, 1, 1,-1,-1,-1,-1},
  { 1,-1, 1, 1, 1, 1,-1, 1},
  { 1,-1,-1, 1,-1, 1, 1,-1},
  { 1,-1, 1, 1, 1, 1,-1, 1},
  { 1,-1,-1, 1,-1, 1, 1,-1},
  { 1, 1,-1, 1, 1,-1, 1, 1},
  { 1, 1,-1, 1, 1,-1, 1, 1}};

__device__ __forceinline__ float fast_tanh(float v) {
  float e = __expf(2.f * v);
  return 1.f - 2.f / (e + 1.f);
}
__device__ __forceinline__ float fast_sig(float v) {
  return 1.f / (1.f + __expf(-v));
}
__device__ __forceinline__ unsigned int bf16_rne(float v) {
  unsigned int u = __float_as_uint(v);
  return (u + 0x7FFFu + ((u >> 16) & 1u)) >> 16;
}

// ---------------------------------------------------------------------------
// prep: build A fragments in per-lane MFMA layout + softmax mix.
// A_pack[p][f][t=dy*3+dx][lane][e]:  m=lane&15=(zoff*8+i), k-quads per lane
// group g=lane>>4: e<4 -> k=g*4+e ; e>=4 -> k=g*4+16+(e-4).  k=(zl*8+j).
// A[m,k] = W_eff[i][j][dz=zl-zoff][dy][dx], zero outside dz in [0,2].
__global__ void prep_kernel(const float* __restrict__ all_weights,   // [F][P][27][8]
                            const float* __restrict__ mix_logits,    // [P][F][F]
                            unsigned short* __restrict__ Apack,
                            float* __restrict__ mix) {
  int idx = blockIdx.x * 256 + threadIdx.x;
  if (idx < APACK_SZ) {
    int e = idx & 7;
    int l = (idx >> 3) & 63;
    int rest = idx >> 9;        // (p*8+f)*9 + t
    int t = rest % 9;
    int fp = rest / 9;          // p*8+f
    int f = fp & 7, p = fp >> 3;
    int g = l >> 4, m = l & 15;
    int zoff = m >> 3, i = m & 7;
    int kk = g*4 + (e & 3) + ((e >= 4) ? 16 : 0);
    int zl = kk >> 3, j = kk & 7;
    int dz = zl - zoff;
    float val = 0.f;
    if (dz >= 0 && dz <= 2)
      val = c_s[i][j] * all_weights[((f*P_ + p)*27 + (dz*9 + t))*8 + c_k[i][j]];
    Apack[idx] = (unsigned short)bf16_rne(val);
  }
  if (blockIdx.x == 0 && threadIdx.x < P_*F_) {
    int p = threadIdx.x / F_, g = threadIdx.x % F_;
    const float* row = &mix_logits[(p*F_ + g)*F_];
    float mx = row[0];
    for (int f = 1; f < F_; ++f) mx = fmaxf(mx, row[f]);
    float e[F_]; float sum = 0.f;
    for (int f = 0; f < F_; ++f) { e[f] = __expf(row[f] - mx); sum += e[f]; }
    float inv = 1.f / sum;
    for (int f = 0; f < F_; ++f) mix[(p*F_ + g)*F_ + f] = e[f] * inv;
  }
}

// ---------------------------------------------------------------------------
// MFMA conv + tanh.  Block: (b, f, z-tile of 2, y-tile of 16) x full 32 x.
// LDS table: point (y' in 18, x' in 34) -> 32 k (zl*8+j) bf16, 80 B stride.
// Point layout (64 B data + 16 pad): 4 slots of 16 B; slot s holds quads
// (s, s+4); quad q = k>>2, bytes (k&3)*2.  Lane group g reads slot g -> b128.
// One __syncthreads; 9 taps x 2 xh MFMAs per y-row per wave.
#define TPTS 612     // 18*34 points
#define PSTR 20      // dwords per point (80 B)

__global__ __launch_bounds__(256, 3)
void conv_kernel(const float* __restrict__ xsrc,
                 float* __restrict__ y,
                 const unsigned short* __restrict__ Apack,
                 const float* __restrict__ biases,   // [F][P][8]
                 int p) {
  __shared__ __align__(16) unsigned int xk[TPTS * PSTR];   // 48960 B

  int bid = blockIdx.x;
  int yt = bid & 1;
  int zt = (bid >> 1) & 15;
  int f  = (bid >> 5) & 7;
  int b  =  bid >> 8;
  int z0 = zt * 2, y0 = yt * 16;
  int tid  = threadIdx.x;
  int lane = tid & 63;
  int wid  = tid >> 6;
  int g    = lane >> 4;
  int ln   = lane & 15;

  // A fragments: 9 taps x 16 B per lane (coalesced global, L1/L2-hot)
  short8v a[9];
  const unsigned short* ap = Apack + (size_t)((p*8 + f) * 9) * 512;
  #pragma unroll
  for (int t = 0; t < 9; ++t)
    a[t] = *(const short8v*)(ap + (t*64 + lane)*8);

  const float* xb = xsrc + b*SB_ + f*SF_;

  // ---- stage x tile as bf16 [point][k] ----
  for (int q = 0; q < 8; ++q) {            // q = zl*2 + jq
    int zl = q >> 1, jq = q & 1;
    int gz = z0 - 2 + zl;
    const float* xj = xb + (jq*4)*G3_ + gz*1024;
    for (int ptl = tid; ptl < TPTS; ptl += 256) {
      int yp = ptl / 34;
      int xc = ptl - yp*34;
      int xq = xc - 2;                     // x' in -2..31
      int gy = y0 - 2 + yp;
      float v0 = 0.f, v1 = 0.f, v2 = 0.f, v3 = 0.f;
      if (gz >= 0 && gy >= 0 && xq >= 0) {
        const float* s = xj + gy*32 + xq;
        v0 = s[0]; v1 = s[G3_]; v2 = s[2*G3_]; v3 = s[3*G3_];
      }
      unsigned int d0 = bf16_rne(v0) | (bf16_rne(v1) << 16);
      unsigned int d1 = bf16_rne(v2) | (bf16_rne(v3) << 16);
      unsigned int* dst = &xk[ptl*PSTR + (q & 3)*4 + (q >> 2)*2];
      dst[0] = d0; dst[1] = d1;
    }
  }
  __syncthreads();

  // ---- compute: wave wid owns y rows 4*wid..4*wid+3, both x halves ----
  const float* bb = biases + (f*P_ + p)*8;
  float bias[4];
  #pragma unroll
  for (int r = 0; r < 4; ++r) bias[r] = bb[(g & 1)*4 + r];
  int zoff = g >> 1;

  for (int yi = 0; yi < 4; ++yi) {
    int yr = wid*4 + yi;
    f32x4 acc0 = {0.f,0.f,0.f,0.f}, acc1 = {0.f,0.f,0.f,0.f};
    #pragma unroll
    for (int dy = 0; dy < 3; ++dy) {
      int prow = (yr + dy)*34;             // y'+2 = yr+dy
      #pragma unroll
      for (int dx = 0; dx < 3; ++dx) {
        int t = dy*3 + dx;
        int pt0 = prow + ln + dx;          // xh=0 window
        short8v b0 = *(const short8v*)&xk[pt0*PSTR + g*4];
        short8v b1 = *(const short8v*)&xk[(pt0 + 16)*PSTR + g*4];
        acc0 = __builtin_amdgcn_mfma_f32_16x16x32_bf16(a[t], b0, acc0, 0, 0, 0);
        acc1 = __builtin_amdgcn_mfma_f32_16x16x32_bf16(a[t], b1, acc1, 0, 0, 0);
      }
    }
    // D layout: col = lane&15 = x, row = 4g+r = (zoff*8 + i)
    float* yb = y + b*SB_ + f*SF_ + (z0 + zoff)*1024 + (y0 + yr)*32 + ln;
    #pragma unroll
    for (int r = 0; r < 4; ++r) {
      int i = (g & 1)*4 + r;
      float* ybi = yb + i*G3_;
      ybi[0]  = fast_tanh(acc0[r] + bias[r]);
      ybi[16] = fast_tanh(acc1[r] + bias[r]);
    }
  }
}

// ---------------------------------------------------------------------------
// cross-field mix + residual: X[b,g,i,s] = a*xb + (1-a)*sum_f mix[g,f]*Y[b,f,i,s]
__global__ void mix_kernel(const float* __restrict__ ybuf,
                           const float* __restrict__ xbsrc,
                           float* __restrict__ xdst,
                           const float* __restrict__ mix,
                           const float* __restrict__ pal,
                           int p) {
  int tid = blockIdx.x * blockDim.x + threadIdx.x;   // 1,048,576 total
  int s4 = tid & 8191;            // G3/4
  int i  = (tid >> 13) & 7;
  int b  =  tid >> 16;
  int base = b*SB_ + i*G3_ + s4*4;
  float a  = fast_sig(pal[p]);
  float na = 1.f - a;

  float4 yv[8];
  #pragma unroll
  for (int ff = 0; ff < 8; ++ff) yv[ff] = *(const float4*)(ybuf + base + ff*SF_);

  #pragma unroll
  for (int g = 0; g < 8; ++g) {
    float4 xb = *(const float4*)(xbsrc + base + g*SF_);
    float sx = 0.f, sy = 0.f, sz = 0.f, sw = 0.f;
    #pragma unroll
    for (int ff = 0; ff < 8; ++ff) {
      float m = mix[(p*8 + g)*8 + ff];
      sx = fmaf(m, yv[ff].x, sx);
      sy = fmaf(m, yv[ff].y, sy);
      sz = fmaf(m, yv[ff].z, sz);
      sw = fmaf(m, yv[ff].w, sw);
    }
    float4 o;
    o.x = a*xb.x + na*sx;  o.y = a*xb.y + na*sy;
    o.z = a*xb.z + na*sz;  o.w = a*xb.w + na*sw;
    *(float4*)(xdst + base + g*SF_) = o;
  }
}

// ---------------------------------------------------------------------------
// final pass mix fused with the output gate:
//   xfin = a*xb + (1-a)*(M y);  gate = sig(gw*old+gb);  out = gate*old + (1-gate)*xfin
__global__ void mixgate_kernel(const float* __restrict__ ybuf,
                               const float* __restrict__ xbsrc,
                               const float* __restrict__ state,
                               float* __restrict__ out,
                               const float* __restrict__ mix,
                               const float* __restrict__ pal,
                               const float* __restrict__ gw,
                               const float* __restrict__ gb,
                               int p) {
  int tid = blockIdx.x * blockDim.x + threadIdx.x;
  int s4 = tid & 8191;
  int i  = (tid >> 13) & 7;
  int b  =  tid >> 16;
  int base = b*SB_ + i*G3_ + s4*4;
  float a  = fast_sig(pal[p]);
  float na = 1.f - a;

  float4 yv[8];
  #pragma unroll
  for (int ff = 0; ff < 8; ++ff) yv[ff] = *(const float4*)(ybuf + base + ff*SF_);

  #pragma unroll
  for (int g = 0; g < 8; ++g) {
    float4 xb = *(const float4*)(xbsrc + base + g*SF_);
    float4 st = *(const float4*)(state + base + g*SF_);
    float sx = 0.f, sy = 0.f, sz = 0.f, sw = 0.f;
    #pragma unroll
    for (int ff = 0; ff < 8; ++ff) {
      float m = mix[(p*8 + g)*8 + ff];
      sx = fmaf(m, yv[ff].x, sx);
      sy = fmaf(m, yv[ff].y, sy);
      sz = fmaf(m, yv[ff].z, sz);
      sw = fmaf(m, yv[ff].w, sw);
    }
    float xfx = a*xb.x + na*sx, xfy = a*xb.y + na*sy;
    float xfz = a*xb.z + na*sz, xfw = a*xb.w + na*sw;
    float w = gw[g*8 + i], bb = gb[g*8 + i];
    float4 r;
    { float gt = fast_sig(w*st.x + bb); r.x = gt*st.x + (1.f-gt)*xfx; }
    { float gt = fast_sig(w*st.y + bb); r.y = gt*st.y + (1.f-gt)*xfy; }
    { float gt = fast_sig(w*st.z + bb); r.z = gt*st.z + (1.f-gt)*xfz; }
    { float gt = fast_sig(w*st.w + bb); r.w = gt*st.w + (1.f-gt)*xfw; }
    *(float4*)(out + base + g*SF_) = r;
  }
}

// ---------------------------------------------------------------------------
extern "C" void kernel_launch(void* const* d_in, const int* in_sizes, int n_in,
                              void* d_out, int out_size, void* d_ws, size_t ws_size,
                              hipStream_t stream) {
  (void)in_sizes; (void)n_in; (void)out_size; (void)ws_size;
  const float* state       = (const float*)d_in[0];
  const float* all_weights = (const float*)d_in[1];
  const float* all_biases  = (const float*)d_in[2];
  const float* mix_logits  = (const float*)d_in[3];
  const float* pal         = (const float*)d_in[4];
  const float* gw          = (const float*)d_in[5];
  const float* gb          = (const float*)d_in[6];
  float* out = (float*)d_out;

  // ws layout: X (N_ f32) | Apack (147456 ushort) | mix (256 f32)
  float* X = (float*)d_ws;
  unsigned short* Apack = (unsigned short*)(X + N_);
  float* mixb = (float*)(Apack + APACK_SZ);
  float* Y    = out;   // d_out doubles as y scratch; overwritten by mixgate

  prep_kernel<<<dim3(APACK_SZ/256), dim3(256), 0, stream>>>(
      all_weights, mix_logits, Apack, mixb);

  for (int p = 0; p < P_; ++p) {
    const float* xcur = (p == 0) ? state : X;   // x_before / conv input
    conv_kernel<<<dim3(B_*F_*16*2), dim3(256), 0, stream>>>(
        xcur, Y, Apack, all_biases, p);
    if (p < P_ - 1) {
      mix_kernel<<<dim3((B_*C_*(G3_/4))/256), dim3(256), 0, stream>>>(
          Y, xcur, X, mixb, pal, p);
    } else {
      mixgate_kernel<<<dim3((B_*C_*(G3_/4))/256), dim3(256), 0, stream>>>(
          Y, X, state, out, mixb, pal, gw, gb, p);
    }
  }
}

// Round 5
// 635.198 us; speedup vs baseline: 4.1277x; 1.0878x over previous
//
#include <hip/hip_runtime.h>
#include <math.h>

// Problem constants (from reference setup_inputs)
#define B_  16
#define F_  8
#define C_  8          // multivector components
#define G_  32
#define G3_ 32768      // G^3
#define P_  4
#define N_  (B_*F_*C_*G3_)   // 33554432 floats = 128 MiB
#define SF_ (C_*G3_)         // field stride   262144
#define SB_ (F_*SF_)         // batch stride  2097152
#define APACK_SZ (P_*F_*9*64*8)  // 147456 ushort (bf16 A fragments)

typedef __attribute__((ext_vector_type(8))) short short8v;
typedef __attribute__((ext_vector_type(4))) float f32x4;

// Cl(3,0) Cayley: for each (i,j) exactly one k with sign s: W_eff[i,j,c] = s*w[c,k]
__device__ __constant__ int c_k[8][8] = {
  {0,1,2,3,4,5,6,7},
  {1,0,4,5,2,3,7,6},
  {2,4,0,6,1,7,3,5},
  {3,5,6,0,7,1,2,4},
  {4,2,1,7,0,6,5,3},
  {5,3,7,1,6,0,4,2},
  {6,7,3,2,5,4,0,1},
  {7,6,5,4,3,2,1,0}};
__device__ __constant__ float c_s[8][8] = {
  { 1, 1, 1, 1,-1,-1,-1,-1},
  { 1, 1, 1, 1,-1,-1,-1,-1},
  { 1,-1, 1, 1, 1, 1,-1, 1},
  { 1,-1,-1, 1,-1, 1, 1,-1},
  { 1,-1, 1, 1, 1, 1,-1, 1},
  { 1,-1,-1, 1,-1, 1, 1,-1},
  { 1, 1,-1, 1, 1,-1, 1, 1},
  { 1, 1,-1, 1, 1,-1, 1, 1}};

__device__ __forceinline__ float fast_tanh(float v) {
  float e = __expf(2.f * v);
  return 1.f - 2.f / (e + 1.f);
}
__device__ __forceinline__ float fast_sig(float v) {
  return 1.f / (1.f + __expf(-v));
}
__device__ __forceinline__ unsigned int bf16_rne(float v) {
  unsigned int u = __float_as_uint(v);
  return (u + 0x7FFFu + ((u >> 16) & 1u)) >> 16;
}
__device__ __forceinline__ unsigned int pk_bf16(float a, float b) {
  unsigned int d;
  asm("v_cvt_pk_bf16_f32 %0, %1, %2" : "=v"(d) : "v"(a), "v"(b));
  return d;   // lo = bf16(a), hi = bf16(b)
}

// ---------------------------------------------------------------------------
// prep: build A fragments in per-lane MFMA layout + softmax mix.
// A_pack[p][f][t=dy*3+dx][lane][e]:  m=lane&15=(zoff*8+i), k-quads per lane
// group g=lane>>4: e<4 -> k=g*4+e ; e>=4 -> k=g*4+16+(e-4).  k=(zl*8+j).
// A[m,k] = W_eff[i][j][dz=zl-zoff][dy][dx], zero outside dz in [0,2].
__global__ void prep_kernel(const float* __restrict__ all_weights,   // [F][P][27][8]
                            const float* __restrict__ mix_logits,    // [P][F][F]
                            unsigned short* __restrict__ Apack,
                            float* __restrict__ mix) {
  int idx = blockIdx.x * 256 + threadIdx.x;
  if (idx < APACK_SZ) {
    int e = idx & 7;
    int l = (idx >> 3) & 63;
    int rest = idx >> 9;        // (p*8+f)*9 + t
    int t = rest % 9;
    int fp = rest / 9;          // p*8+f
    int f = fp & 7, p = fp >> 3;
    int g = l >> 4, m = l & 15;
    int zoff = m >> 3, i = m & 7;
    int kk = g*4 + (e & 3) + ((e >= 4) ? 16 : 0);
    int zl = kk >> 3, j = kk & 7;
    int dz = zl - zoff;
    float val = 0.f;
    if (dz >= 0 && dz <= 2)
      val = c_s[i][j] * all_weights[((f*P_ + p)*27 + (dz*9 + t))*8 + c_k[i][j]];
    Apack[idx] = (unsigned short)bf16_rne(val);
  }
  if (blockIdx.x == 0 && threadIdx.x < P_*F_) {
    int p = threadIdx.x / F_, g = threadIdx.x % F_;
    const float* row = &mix_logits[(p*F_ + g)*F_];
    float mx = row[0];
    for (int f = 1; f < F_; ++f) mx = fmaxf(mx, row[f]);
    float e[F_]; float sum = 0.f;
    for (int f = 0; f < F_; ++f) { e[f] = __expf(row[f] - mx); sum += e[f]; }
    float inv = 1.f / sum;
    for (int f = 0; f < F_; ++f) mix[(p*F_ + g)*F_ + f] = e[f] * inv;
  }
}

// ---------------------------------------------------------------------------
// MFMA conv + tanh.  Block: (b, f, z-tile of 2, y-tile of 16) x full 32 x.
// LDS table: point (y' in 18, x' in 34) -> 32 k (zl*8+j) bf16, 64 B stride,
// XOR-swizzled on dword bits 2-3 by (pt&3) to restore bank entropy.
// Lane group g reads its 16 B k-quad -> ds_read_b128; x-half 2 at +1024 B.
#define TPTS 612     // 18*34 points
// LDS dwords = TPTS*16 = 9792 -> 39168 B -> 4 blocks/CU

__global__ __launch_bounds__(256, 4)
void conv_kernel(const float* __restrict__ xsrc,
                 float* __restrict__ y,
                 const unsigned short* __restrict__ Apack,
                 const float* __restrict__ biases,   // [F][P][8]
                 int p) {
  __shared__ __align__(16) unsigned int xk[TPTS * 16];   // 39168 B

  int bid = blockIdx.x;
  int yt = bid & 1;
  int zt = (bid >> 1) & 15;
  int f  = (bid >> 5) & 7;
  int b  =  bid >> 8;
  int z0 = zt * 2, y0 = yt * 16;
  int tid  = threadIdx.x;
  int lane = tid & 63;
  int wid  = tid >> 6;
  int g    = lane >> 4;
  int ln   = lane & 15;

  // A fragments: 9 taps x 16 B per lane (coalesced global, L2-hot)
  short8v a[9];
  const unsigned short* ap = Apack + (size_t)((p*8 + f) * 9) * 512;
  #pragma unroll
  for (int t = 0; t < 9; ++t)
    a[t] = *(const short8v*)(ap + (t*64 + lane)*8);

  const float* xb = xsrc + b*SB_ + f*SF_;

  // ---- stage x tile as bf16 [point][k], swizzled ----
  for (int q = 0; q < 8; ++q) {            // q = zl*2 + jq
    int zl = q >> 1, jq = q & 1;
    int gz = z0 - 2 + zl;
    const float* xj = xb + (jq*4)*G3_ + gz*1024;
    int shi = (q >> 2) * 2;                // dword sub-slot within quad
    int sq  = (q & 3) * 4;                 // k-quad base slot
    for (int ptl = tid; ptl < TPTS; ptl += 256) {
      int row = ptl / 34;                  // magic-mul
      int xc  = ptl - row * 34;
      int gy = y0 - 2 + row;
      int gx = xc - 2;
      float v0 = 0.f, v1 = 0.f, v2 = 0.f, v3 = 0.f;
      if (gz >= 0 && gy >= 0 && gx >= 0) {
        const float* s = xj + gy*32 + gx;
        v0 = s[0]; v1 = s[G3_]; v2 = s[2*G3_]; v3 = s[3*G3_];
      }
      unsigned int d0 = pk_bf16(v0, v1);
      unsigned int d1 = pk_bf16(v2, v3);
      unsigned int* dst = &xk[ptl*16 + (sq ^ ((ptl & 3) << 2)) + shi];
      dst[0] = d0; dst[1] = d1;
    }
  }
  __syncthreads();

  // ---- compute: wave wid owns y rows 4*wid..4*wid+3, both x halves ----
  const float* bb = biases + (f*P_ + p)*8;
  float bias[4];
  #pragma unroll
  for (int r = 0; r < 4; ++r) bias[r] = bb[(g & 1)*4 + r];
  int zoff = g >> 1;
  int g4 = g * 4;

  for (int yi = 0; yi < 4; ++yi) {
    int yr = wid*4 + yi;
    f32x4 acc0 = {0.f,0.f,0.f,0.f}, acc1 = {0.f,0.f,0.f,0.f};
    #pragma unroll
    for (int dy = 0; dy < 3; ++dy) {
      int prow = (yr + dy)*34;             // y'+2 = yr+dy
      #pragma unroll
      for (int dx = 0; dx < 3; ++dx) {
        int t = dy*3 + dx;
        int pt0 = prow + ln + dx;          // xh=0 window point index
        int dwb = pt0*16 + (g4 ^ ((pt0 & 3) << 2));
        short8v b0 = *(const short8v*)&xk[dwb];
        short8v b1 = *(const short8v*)&xk[dwb + 256];   // pt0+16: same swizzle
        acc0 = __builtin_amdgcn_mfma_f32_16x16x32_bf16(a[t], b0, acc0, 0, 0, 0);
        acc1 = __builtin_amdgcn_mfma_f32_16x16x32_bf16(a[t], b1, acc1, 0, 0, 0);
      }
    }
    // D layout: col = lane&15 = x, row = 4g+r = (zoff*8 + i)
    float* yb = y + b*SB_ + f*SF_ + (z0 + zoff)*1024 + (y0 + yr)*32 + ln;
    #pragma unroll
    for (int r = 0; r < 4; ++r) {
      int i = (g & 1)*4 + r;
      float* ybi = yb + i*G3_;
      ybi[0]  = fast_tanh(acc0[r] + bias[r]);
      ybi[16] = fast_tanh(acc1[r] + bias[r]);
    }
  }
}

// ---------------------------------------------------------------------------
// cross-field mix + residual: X[b,g,i,s] = a*xb + (1-a)*sum_f mix[g,f]*Y[b,f,i,s]
__global__ void mix_kernel(const float* __restrict__ ybuf,
                           const float* __restrict__ xbsrc,
                           float* __restrict__ xdst,
                           const float* __restrict__ mix,
                           const float* __restrict__ pal,
                           int p) {
  int tid = blockIdx.x * blockDim.x + threadIdx.x;   // 1,048,576 total
  int s4 = tid & 8191;            // G3/4
  int i  = (tid >> 13) & 7;
  int b  =  tid >> 16;
  int base = b*SB_ + i*G3_ + s4*4;
  float a  = fast_sig(pal[p]);
  float na = 1.f - a;

  float4 yv[8];
  #pragma unroll
  for (int ff = 0; ff < 8; ++ff) yv[ff] = *(const float4*)(ybuf + base + ff*SF_);

  #pragma unroll
  for (int g = 0; g < 8; ++g) {
    float4 xb = *(const float4*)(xbsrc + base + g*SF_);
    float sx = 0.f, sy = 0.f, sz = 0.f, sw = 0.f;
    #pragma unroll
    for (int ff = 0; ff < 8; ++ff) {
      float m = mix[(p*8 + g)*8 + ff];
      sx = fmaf(m, yv[ff].x, sx);
      sy = fmaf(m, yv[ff].y, sy);
      sz = fmaf(m, yv[ff].z, sz);
      sw = fmaf(m, yv[ff].w, sw);
    }
    float4 o;
    o.x = a*xb.x + na*sx;  o.y = a*xb.y + na*sy;
    o.z = a*xb.z + na*sz;  o.w = a*xb.w + na*sw;
    *(float4*)(xdst + base + g*SF_) = o;
  }
}

// ---------------------------------------------------------------------------
// final pass mix fused with the output gate:
//   xfin = a*xb + (1-a)*(M y);  gate = sig(gw*old+gb);  out = gate*old + (1-gate)*xfin
__global__ void mixgate_kernel(const float* __restrict__ ybuf,
                               const float* __restrict__ xbsrc,
                               const float* __restrict__ state,
                               float* __restrict__ out,
                               const float* __restrict__ mix,
                               const float* __restrict__ pal,
                               const float* __restrict__ gw,
                               const float* __restrict__ gb,
                               int p) {
  int tid = blockIdx.x * blockDim.x + threadIdx.x;
  int s4 = tid & 8191;
  int i  = (tid >> 13) & 7;
  int b  =  tid >> 16;
  int base = b*SB_ + i*G3_ + s4*4;
  float a  = fast_sig(pal[p]);
  float na = 1.f - a;

  float4 yv[8];
  #pragma unroll
  for (int ff = 0; ff < 8; ++ff) yv[ff] = *(const float4*)(ybuf + base + ff*SF_);

  #pragma unroll
  for (int g = 0; g < 8; ++g) {
    float4 xb = *(const float4*)(xbsrc + base + g*SF_);
    float4 st = *(const float4*)(state + base + g*SF_);
    float sx = 0.f, sy = 0.f, sz = 0.f, sw = 0.f;
    #pragma unroll
    for (int ff = 0; ff < 8; ++ff) {
      float m = mix[(p*8 + g)*8 + ff];
      sx = fmaf(m, yv[ff].x, sx);
      sy = fmaf(m, yv[ff].y, sy);
      sz = fmaf(m, yv[ff].z, sz);
      sw = fmaf(m, yv[ff].w, sw);
    }
    float xfx = a*xb.x + na*sx, xfy = a*xb.y + na*sy;
    float xfz = a*xb.z + na*sz, xfw = a*xb.w + na*sw;
    float w = gw[g*8 + i], bb = gb[g*8 + i];
    float4 r;
    { float gt = fast_sig(w*st.x + bb); r.x = gt*st.x + (1.f-gt)*xfx; }
    { float gt = fast_sig(w*st.y + bb); r.y = gt*st.y + (1.f-gt)*xfy; }
    { float gt = fast_sig(w*st.z + bb); r.z = gt*st.z + (1.f-gt)*xfz; }
    { float gt = fast_sig(w*st.w + bb); r.w = gt*st.w + (1.f-gt)*xfw; }
    *(float4*)(out + base + g*SF_) = r;
  }
}

// ---------------------------------------------------------------------------
extern "C" void kernel_launch(void* const* d_in, const int* in_sizes, int n_in,
                              void* d_out, int out_size, void* d_ws, size_t ws_size,
                              hipStream_t stream) {
  (void)in_sizes; (void)n_in; (void)out_size; (void)ws_size;
  const float* state       = (const float*)d_in[0];
  const float* all_weights = (const float*)d_in[1];
  const float* all_biases  = (const float*)d_in[2];
  const float* mix_logits  = (const float*)d_in[3];
  const float* pal         = (const float*)d_in[4];
  const float* gw          = (const float*)d_in[5];
  const float* gb          = (const float*)d_in[6];
  float* out = (float*)d_out;

  // ws layout: X (N_ f32) | Apack (147456 ushort) | mix (256 f32)
  float* X = (float*)d_ws;
  unsigned short* Apack = (unsigned short*)(X + N_);
  float* mixb = (float*)(Apack + APACK_SZ);
  float* Y    = out;   // d_out doubles as y scratch; overwritten by mixgate

  prep_kernel<<<dim3(APACK_SZ/256), dim3(256), 0, stream>>>(
      all_weights, mix_logits, Apack, mixb);

  for (int p = 0; p < P_; ++p) {
    const float* xcur = (p == 0) ? state : X;   // x_before / conv input
    conv_kernel<<<dim3(B_*F_*16*2), dim3(256), 0, stream>>>(
        xcur, Y, Apack, all_biases, p);
    if (p < P_ - 1) {
      mix_kernel<<<dim3((B_*C_*(G3_/4))/256), dim3(256), 0, stream>>>(
          Y, xcur, X, mixb, pal, p);
    } else {
      mixgate_kernel<<<dim3((B_*C_*(G3_/4))/256), dim3(256), 0, stream>>>(
          Y, X, state, out, mixb, pal, gw, gb, p);
    }
  }
}

// Round 6
// 555.235 us; speedup vs baseline: 4.7221x; 1.1440x over previous
//
#include <hip/hip_runtime.h>
#include <math.h>

// Problem constants (from reference setup_inputs)
#define B_  16
#define F_  8
#define C_  8          // multivector components
#define G_  32
#define G3_ 32768      // G^3
#define P_  4
#define N_  (B_*F_*C_*G3_)   // 33554432 floats = 128 MiB
#define SF_ (C_*G3_)         // field stride   262144
#define SB_ (F_*SF_)         // batch stride  2097152
#define APACK_SZ (P_*F_*9*64*8)  // 147456 ushort (bf16 A fragments)

typedef __attribute__((ext_vector_type(8))) short short8v;
typedef __attribute__((ext_vector_type(4))) float f32x4;

// Cl(3,0) Cayley: for each (i,j) exactly one k with sign s: W_eff[i,j,c] = s*w[c,k]
__device__ __constant__ int c_k[8][8] = {
  {0,1,2,3,4,5,6,7},
  {1,0,4,5,2,3,7,6},
  {2,4,0,6,1,7,3,5},
  {3,5,6,0,7,1,2,4},
  {4,2,1,7,0,6,5,3},
  {5,3,7,1,6,0,4,2},
  {6,7,3,2,5,4,0,1},
  {7,6,5,4,3,2,1,0}};
__device__ __constant__ float c_s[8][8] = {
  { 1, 1, 1, 1,-1,-1,-1,-1},
  { 1, 1, 1, 1,-1,-1,-1,-1},
  { 1,-1, 1, 1, 1, 1,-1, 1},
  { 1,-1,-1, 1,-1, 1, 1,-1},
  { 1,-1, 1, 1, 1, 1,-1, 1},
  { 1,-1,-1, 1,-1, 1, 1,-1},
  { 1, 1,-1, 1, 1,-1, 1, 1},
  { 1, 1,-1, 1, 1,-1, 1, 1}};

__device__ __forceinline__ float fast_tanh(float v) {
  float e = __expf(2.f * v);
  return 1.f - 2.f / (e + 1.f);
}
__device__ __forceinline__ float fast_sig(float v) {
  return 1.f / (1.f + __expf(-v));
}
__device__ __forceinline__ unsigned int bf16_rne(float v) {
  unsigned int u = __float_as_uint(v);
  return (u + 0x7FFFu + ((u >> 16) & 1u)) >> 16;
}
__device__ __forceinline__ unsigned int pk_bf16(float a, float b) {
  unsigned int d;
  asm("v_cvt_pk_bf16_f32 %0, %1, %2" : "=v"(d) : "v"(a), "v"(b));
  return d;   // lo = bf16(a), hi = bf16(b)
}

// ---------------------------------------------------------------------------
// prep: build A fragments in per-lane MFMA layout + softmax mix.
// A_pack[p][f][t=dy*3+dx][lane][e]:  m=lane&15=(zoff*8+i), k-quads per lane
// group g=lane>>4: e<4 -> k=g*4+e ; e>=4 -> k=g*4+16+(e-4).  k=(zl*8+j).
// A[m,k] = W_eff[i][j][dz=zl-zoff][dy][dx], zero outside dz in [0,2].
__global__ void prep_kernel(const float* __restrict__ all_weights,   // [F][P][27][8]
                            const float* __restrict__ mix_logits,    // [P][F][F]
                            unsigned short* __restrict__ Apack,
                            float* __restrict__ mix) {
  int idx = blockIdx.x * 256 + threadIdx.x;
  if (idx < APACK_SZ) {
    int e = idx & 7;
    int l = (idx >> 3) & 63;
    int rest = idx >> 9;        // (p*8+f)*9 + t
    int t = rest % 9;
    int fp = rest / 9;          // p*8+f
    int f = fp & 7, p = fp >> 3;
    int g = l >> 4, m = l & 15;
    int zoff = m >> 3, i = m & 7;
    int kk = g*4 + (e & 3) + ((e >= 4) ? 16 : 0);
    int zl = kk >> 3, j = kk & 7;
    int dz = zl - zoff;
    float val = 0.f;
    if (dz >= 0 && dz <= 2)
      val = c_s[i][j] * all_weights[((f*P_ + p)*27 + (dz*9 + t))*8 + c_k[i][j]];
    Apack[idx] = (unsigned short)bf16_rne(val);
  }
  if (blockIdx.x == 0 && threadIdx.x < P_*F_) {
    int p = threadIdx.x / F_, g = threadIdx.x % F_;
    const float* row = &mix_logits[(p*F_ + g)*F_];
    float mx = row[0];
    for (int f = 1; f < F_; ++f) mx = fmaxf(mx, row[f]);
    float e[F_]; float sum = 0.f;
    for (int f = 0; f < F_; ++f) { e[f] = __expf(row[f] - mx); sum += e[f]; }
    float inv = 1.f / sum;
    for (int f = 0; f < F_; ++f) mix[(p*F_ + g)*F_ + f] = e[f] * inv;
  }
}

// ---------------------------------------------------------------------------
// MFMA conv + tanh.  Block: (b, f, z-tile of 2, y-tile of 8) x full 32 x.
// LDS table: point (y' in 10, x' in 34) -> 32 k (zl*8+j) bf16 = 16 dwords,
// 4 quads; quad qq holds k {8*zl(qq)+4*jq(qq)+0..3} and same +16 (zl+2).
// Quad position swizzled: pos = qq ^ (pt&3).  Reads: ds_read_b128, group g
// reads quad g; x-half 2 at +256 dwords (pt+16, same swizzle).
#define TPTS 340     // 10*34 points
// LDS = 340*64 B = 21760 B -> 7 blocks/CU (28 waves, 87.5%)

__global__ __launch_bounds__(256, 7)
void conv_kernel(const float* __restrict__ xsrc,
                 float* __restrict__ y,
                 const unsigned short* __restrict__ Apack,
                 const float* __restrict__ biases,   // [F][P][8]
                 int p) {
  __shared__ __align__(16) unsigned int xk[TPTS * 16];   // 21760 B

  int bid = blockIdx.x;
  int yt = bid & 3;
  int zt = (bid >> 2) & 15;
  int f  = (bid >> 6) & 7;
  int b  =  bid >> 9;
  int z0 = zt * 2, y0 = yt * 8;
  int tid  = threadIdx.x;
  int lane = tid & 63;
  int wid  = tid >> 6;
  int g    = lane >> 4;
  int ln   = lane & 15;

  const float* xb = xsrc + b*SB_ + f*SF_;

  // pre-zero x-halo points (x'=0,1): 10 rows x 2 pts x 16 dwords
  for (int idx = tid; idx < 10*2*16; idx += 256) {
    int pt = (idx >> 5) * 34 + ((idx >> 4) & 1);
    xk[pt*16 + (idx & 15)] = 0u;
  }

  // ---- stage: 4 qq x 10 rows x 8 chunks of 4 x-points ----
  for (int it = tid; it < 320; it += 256) {
    int qq  = it / 80;                 // quad index
    int r2  = it - qq*80;
    int row = r2 >> 3;
    int c   = r2 & 7;
    int zl = qq >> 1, jq = qq & 1;
    int gz0 = z0 - 2 + zl;             // may be <0; gz0+2 always valid
    int gy  = y0 - 2 + row;            // may be <0
    int gx  = c * 4;
    const float* s0 = xb + (jq*4)*G3_ + gz0*1024 + gy*32 + gx;
    const float* s1 = s0 + 2048;       // plane zl+2
    float4 A0={0,0,0,0},A1={0,0,0,0},A2={0,0,0,0},A3={0,0,0,0};
    float4 B0={0,0,0,0},B1={0,0,0,0},B2={0,0,0,0},B3={0,0,0,0};
    if (gy >= 0) {
      if (gz0 >= 0) {
        A0 = *(const float4*)(s0);
        A1 = *(const float4*)(s0 + G3_);
        A2 = *(const float4*)(s0 + 2*G3_);
        A3 = *(const float4*)(s0 + 3*G3_);
      }
      B0 = *(const float4*)(s1);
      B1 = *(const float4*)(s1 + G3_);
      B2 = *(const float4*)(s1 + 2*G3_);
      B3 = *(const float4*)(s1 + 3*G3_);
    }
    int ptb = row*34 + 2 + gx;
    #define STW(px, a0v,a1v,a2v,a3v,b0v,b1v,b2v,b3v) { \
      uint4 d; d.x = pk_bf16(a0v, a1v); d.y = pk_bf16(a2v, a3v); \
      d.z = pk_bf16(b0v, b1v); d.w = pk_bf16(b2v, b3v); \
      int pt = ptb + px; \
      *(uint4*)&xk[pt*16 + ((qq ^ (pt & 3)) << 2)] = d; }
    STW(0, A0.x,A1.x,A2.x,A3.x, B0.x,B1.x,B2.x,B3.x)
    STW(1, A0.y,A1.y,A2.y,A3.y, B0.y,B1.y,B2.y,B3.y)
    STW(2, A0.z,A1.z,A2.z,A3.z, B0.z,B1.z,B2.z,B3.z)
    STW(3, A0.w,A1.w,A2.w,A3.w, B0.w,B1.w,B2.w,B3.w)
    #undef STW
  }

  // A fragments: 9 taps x 16 B per lane (loaded after staging to cut
  // peak VGPR pressure; overlaps the barrier wait)
  short8v a[9];
  const unsigned short* ap = Apack + (size_t)((p*8 + f) * 9) * 512;
  #pragma unroll
  for (int t = 0; t < 9; ++t)
    a[t] = *(const short8v*)(ap + (t*64 + lane)*8);

  __syncthreads();

  // ---- compute: wave wid owns y rows 2*wid..2*wid+1, both x halves ----
  const float* bb = biases + (f*P_ + p)*8;
  float bias[4];
  #pragma unroll
  for (int r = 0; r < 4; ++r) bias[r] = bb[(g & 1)*4 + r];
  int zoff = g >> 1;

  #pragma unroll
  for (int yi = 0; yi < 2; ++yi) {
    int yr = wid*2 + yi;
    f32x4 acc0 = {0.f,0.f,0.f,0.f}, acc1 = {0.f,0.f,0.f,0.f};
    #pragma unroll
    for (int dy = 0; dy < 3; ++dy) {
      int prow = (yr + dy)*34;             // y'+2 = yr+dy
      #pragma unroll
      for (int dx = 0; dx < 3; ++dx) {
        int t = dy*3 + dx;
        int pt0 = prow + ln + dx;          // xh=0 window point index
        int dwb = pt0*16 + ((g ^ (pt0 & 3)) << 2);
        short8v b0 = *(const short8v*)&xk[dwb];
        short8v b1 = *(const short8v*)&xk[dwb + 256];   // pt0+16: same swizzle
        acc0 = __builtin_amdgcn_mfma_f32_16x16x32_bf16(a[t], b0, acc0, 0, 0, 0);
        acc1 = __builtin_amdgcn_mfma_f32_16x16x32_bf16(a[t], b1, acc1, 0, 0, 0);
      }
    }
    // D layout: col = lane&15 = x, row = 4g+r = (zoff*8 + i)
    float* yb = y + b*SB_ + f*SF_ + (z0 + zoff)*1024 + (y0 + yr)*32 + ln;
    #pragma unroll
    for (int r = 0; r < 4; ++r) {
      int i = (g & 1)*4 + r;
      float* ybi = yb + i*G3_;
      ybi[0]  = fast_tanh(acc0[r] + bias[r]);
      ybi[16] = fast_tanh(acc1[r] + bias[r]);
    }
  }
}

// ---------------------------------------------------------------------------
// cross-field mix + residual: X[b,g,i,s] = a*xb + (1-a)*sum_f mix[g,f]*Y[b,f,i,s]
__global__ void mix_kernel(const float* __restrict__ ybuf,
                           const float* __restrict__ xbsrc,
                           float* __restrict__ xdst,
                           const float* __restrict__ mix,
                           const float* __restrict__ pal,
                           int p) {
  int tid = blockIdx.x * blockDim.x + threadIdx.x;   // 1,048,576 total
  int s4 = tid & 8191;            // G3/4
  int i  = (tid >> 13) & 7;
  int b  =  tid >> 16;
  int base = b*SB_ + i*G3_ + s4*4;
  float a  = fast_sig(pal[p]);
  float na = 1.f - a;

  float4 yv[8];
  #pragma unroll
  for (int ff = 0; ff < 8; ++ff) yv[ff] = *(const float4*)(ybuf + base + ff*SF_);

  #pragma unroll
  for (int g = 0; g < 8; ++g) {
    float4 xb = *(const float4*)(xbsrc + base + g*SF_);
    float sx = 0.f, sy = 0.f, sz = 0.f, sw = 0.f;
    #pragma unroll
    for (int ff = 0; ff < 8; ++ff) {
      float m = mix[(p*8 + g)*8 + ff];
      sx = fmaf(m, yv[ff].x, sx);
      sy = fmaf(m, yv[ff].y, sy);
      sz = fmaf(m, yv[ff].z, sz);
      sw = fmaf(m, yv[ff].w, sw);
    }
    float4 o;
    o.x = a*xb.x + na*sx;  o.y = a*xb.y + na*sy;
    o.z = a*xb.z + na*sz;  o.w = a*xb.w + na*sw;
    *(float4*)(xdst + base + g*SF_) = o;
  }
}

// ---------------------------------------------------------------------------
// final pass mix fused with the output gate:
//   xfin = a*xb + (1-a)*(M y);  gate = sig(gw*old+gb);  out = gate*old + (1-gate)*xfin
__global__ void mixgate_kernel(const float* __restrict__ ybuf,
                               const float* __restrict__ xbsrc,
                               const float* __restrict__ state,
                               float* __restrict__ out,
                               const float* __restrict__ mix,
                               const float* __restrict__ pal,
                               const float* __restrict__ gw,
                               const float* __restrict__ gb,
                               int p) {
  int tid = blockIdx.x * blockDim.x + threadIdx.x;
  int s4 = tid & 8191;
  int i  = (tid >> 13) & 7;
  int b  =  tid >> 16;
  int base = b*SB_ + i*G3_ + s4*4;
  float a  = fast_sig(pal[p]);
  float na = 1.f - a;

  float4 yv[8];
  #pragma unroll
  for (int ff = 0; ff < 8; ++ff) yv[ff] = *(const float4*)(ybuf + base + ff*SF_);

  #pragma unroll
  for (int g = 0; g < 8; ++g) {
    float4 xb = *(const float4*)(xbsrc + base + g*SF_);
    float4 st = *(const float4*)(state + base + g*SF_);
    float sx = 0.f, sy = 0.f, sz = 0.f, sw = 0.f;
    #pragma unroll
    for (int ff = 0; ff < 8; ++ff) {
      float m = mix[(p*8 + g)*8 + ff];
      sx = fmaf(m, yv[ff].x, sx);
      sy = fmaf(m, yv[ff].y, sy);
      sz = fmaf(m, yv[ff].z, sz);
      sw = fmaf(m, yv[ff].w, sw);
    }
    float xfx = a*xb.x + na*sx, xfy = a*xb.y + na*sy;
    float xfz = a*xb.z + na*sz, xfw = a*xb.w + na*sw;
    float w = gw[g*8 + i], bb = gb[g*8 + i];
    float4 r;
    { float gt = fast_sig(w*st.x + bb); r.x = gt*st.x + (1.f-gt)*xfx; }
    { float gt = fast_sig(w*st.y + bb); r.y = gt*st.y + (1.f-gt)*xfy; }
    { float gt = fast_sig(w*st.z + bb); r.z = gt*st.z + (1.f-gt)*xfz; }
    { float gt = fast_sig(w*st.w + bb); r.w = gt*st.w + (1.f-gt)*xfw; }
    *(float4*)(out + base + g*SF_) = r;
  }
}

// ---------------------------------------------------------------------------
extern "C" void kernel_launch(void* const* d_in, const int* in_sizes, int n_in,
                              void* d_out, int out_size, void* d_ws, size_t ws_size,
                              hipStream_t stream) {
  (void)in_sizes; (void)n_in; (void)out_size; (void)ws_size;
  const float* state       = (const float*)d_in[0];
  const float* all_weights = (const float*)d_in[1];
  const float* all_biases  = (const float*)d_in[2];
  const float* mix_logits  = (const float*)d_in[3];
  const float* pal         = (const float*)d_in[4];
  const float* gw          = (const float*)d_in[5];
  const float* gb          = (const float*)d_in[6];
  float* out = (float*)d_out;

  // ws layout: X (N_ f32) | Apack (147456 ushort) | mix (256 f32)
  float* X = (float*)d_ws;
  unsigned short* Apack = (unsigned short*)(X + N_);
  float* mixb = (float*)(Apack + APACK_SZ);
  float* Y    = out;   // d_out doubles as y scratch; overwritten by mixgate

  prep_kernel<<<dim3(APACK_SZ/256), dim3(256), 0, stream>>>(
      all_weights, mix_logits, Apack, mixb);

  for (int p = 0; p < P_; ++p) {
    const float* xcur = (p == 0) ? state : X;   // x_before / conv input
    conv_kernel<<<dim3(B_*F_*16*4), dim3(256), 0, stream>>>(
        xcur, Y, Apack, all_biases, p);
    if (p < P_ - 1) {
      mix_kernel<<<dim3((B_*C_*(G3_/4))/256), dim3(256), 0, stream>>>(
          Y, xcur, X, mixb, pal, p);
    } else {
      mixgate_kernel<<<dim3((B_*C_*(G3_/4))/256), dim3(256), 0, stream>>>(
          Y, X, state, out, mixb, pal, gw, gb, p);
    }
  }
}

// Round 7
// 393.209 us; speedup vs baseline: 6.6679x; 1.4121x over previous
//
#include <hip/hip_runtime.h>
#include <math.h>

// Problem constants (from reference setup_inputs)
#define B_  16
#define F_  8
#define C_  8          // multivector components
#define G_  32
#define G3_ 32768      // G^3
#define P_  4
#define N_  (B_*F_*C_*G3_)   // 33554432 elems
#define SF_ (C_*G3_)         // field stride   262144
#define SB_ (F_*SF_)         // batch stride  2097152
#define APACK_SZ (P_*F_*9*64*8)  // 147456 ushort (bf16 A fragments)

typedef __attribute__((ext_vector_type(8))) short short8v;
typedef __attribute__((ext_vector_type(4))) float f32x4;
typedef unsigned short u16;
typedef unsigned int u32;

// Cl(3,0) Cayley: for each (i,j) exactly one k with sign s: W_eff[i,j,c] = s*w[c,k]
__device__ __constant__ int c_k[8][8] = {
  {0,1,2,3,4,5,6,7},
  {1,0,4,5,2,3,7,6},
  {2,4,0,6,1,7,3,5},
  {3,5,6,0,7,1,2,4},
  {4,2,1,7,0,6,5,3},
  {5,3,7,1,6,0,4,2},
  {6,7,3,2,5,4,0,1},
  {7,6,5,4,3,2,1,0}};
__device__ __constant__ float c_s[8][8] = {
  { 1, 1, 1, 1,-1,-1,-1,-1},
  { 1, 1, 1, 1,-1,-1,-1,-1},
  { 1,-1, 1, 1, 1, 1,-1, 1},
  { 1,-1,-1, 1,-1, 1, 1,-1},
  { 1,-1, 1, 1, 1, 1,-1, 1},
  { 1,-1,-1, 1,-1, 1, 1,-1},
  { 1, 1,-1, 1, 1,-1, 1, 1},
  { 1, 1,-1, 1, 1,-1, 1, 1}};

__device__ __forceinline__ float fast_tanh(float v) {
  float e = __expf(2.f * v);
  return 1.f - 2.f / (e + 1.f);
}
__device__ __forceinline__ float fast_sig(float v) {
  return 1.f / (1.f + __expf(-v));
}
__device__ __forceinline__ u32 bf16_rne(float v) {
  u32 u = __float_as_uint(v);
  return (u + 0x7FFFu + ((u >> 16) & 1u)) >> 16;
}
__device__ __forceinline__ u32 pk_bf16(float a, float b) {
  u32 d;
  asm("v_cvt_pk_bf16_f32 %0, %1, %2" : "=v"(d) : "v"(a), "v"(b));
  return d;   // lo = bf16(a), hi = bf16(b)
}
__device__ __forceinline__ float bl(u32 u) { return __uint_as_float(u << 16); }
__device__ __forceinline__ float bh(u32 u) { return __uint_as_float(u & 0xffff0000u); }

// ---------------------------------------------------------------------------
// prep: build A fragments in per-lane MFMA layout + softmax mix.
// A_pack[p][f][t=dy*3+dx][lane][e]:  m=lane&15=(zoff*8+i), k-quads per lane
// group g=lane>>4: e<4 -> k=g*4+e ; e>=4 -> k=g*4+16+(e-4).  k=(zl*8+j).
__global__ void prep_kernel(const float* __restrict__ all_weights,   // [F][P][27][8]
                            const float* __restrict__ mix_logits,    // [P][F][F]
                            u16* __restrict__ Apack,
                            float* __restrict__ mix) {
  int idx = blockIdx.x * 256 + threadIdx.x;
  if (idx < APACK_SZ) {
    int e = idx & 7;
    int l = (idx >> 3) & 63;
    int rest = idx >> 9;        // (p*8+f)*9 + t
    int t = rest % 9;
    int fp = rest / 9;          // p*8+f
    int f = fp & 7, p = fp >> 3;
    int g = l >> 4, m = l & 15;
    int zoff = m >> 3, i = m & 7;
    int kk = g*4 + (e & 3) + ((e >= 4) ? 16 : 0);
    int zl = kk >> 3, j = kk & 7;
    int dz = zl - zoff;
    float val = 0.f;
    if (dz >= 0 && dz <= 2)
      val = c_s[i][j] * all_weights[((f*P_ + p)*27 + (dz*9 + t))*8 + c_k[i][j]];
    Apack[idx] = (u16)bf16_rne(val);
  }
  if (blockIdx.x == 0 && threadIdx.x < P_*F_) {
    int p = threadIdx.x / F_, g = threadIdx.x % F_;
    const float* row = &mix_logits[(p*F_ + g)*F_];
    float mx = row[0];
    for (int f = 1; f < F_; ++f) mx = fmaxf(mx, row[f]);
    float e[F_]; float sum = 0.f;
    for (int f = 0; f < F_; ++f) { e[f] = __expf(row[f] - mx); sum += e[f]; }
    float inv = 1.f / sum;
    for (int f = 0; f < F_; ++f) mix[(p*F_ + g)*F_ + f] = e[f] * inv;
  }
}

// ---------------------------------------------------------------------------
// MFMA conv + tanh.  Block: (b, f, z-tile of 2, y-tile of 8) x full 32 x.
// LDS: point (y' in 10, x' in 34) -> 32 k bf16 = 16 dwords, quad qq at
// position qq^(pt&3).  BIN=true: input X is bf16 (perm interleave);
// BIN=false: input f32 (cvt_pk).  Output Y bf16.
#define TPTS 340     // 10*34 points

template<bool BIN>
__global__ __launch_bounds__(256, 7)
void conv_kernel(const void* __restrict__ xsrc_,
                 u16* __restrict__ y,
                 const u16* __restrict__ Apack,
                 const float* __restrict__ biases,   // [F][P][8]
                 int p) {
  __shared__ __align__(16) u32 xk[TPTS * 16];   // 21760 B

  int bid = blockIdx.x;
  int yt = bid & 3;
  int zt = (bid >> 2) & 15;
  int f  = (bid >> 6) & 7;
  int b  =  bid >> 9;
  int z0 = zt * 2, y0 = yt * 8;
  int tid  = threadIdx.x;
  int lane = tid & 63;
  int wid  = tid >> 6;
  int g    = lane >> 4;
  int ln   = lane & 15;

  // pre-zero x-halo points (x'=0,1): 10 rows x 2 pts x 16 dwords
  for (int idx = tid; idx < 10*2*16; idx += 256) {
    int pt = (idx >> 5) * 34 + ((idx >> 4) & 1);
    xk[pt*16 + (idx & 15)] = 0u;
  }

  // ---- stage: 4 qq x 10 rows x 8 chunks of 4 x-points ----
  for (int it = tid; it < 320; it += 256) {
    int qq  = it / 80;                 // quad index
    int r2  = it - qq*80;
    int row = r2 >> 3;
    int c   = r2 & 7;
    int zl = qq >> 1, jq = qq & 1;
    int gz0 = z0 - 2 + zl;             // may be <0; gz0+2 always valid
    int gy  = y0 - 2 + row;            // may be <0
    int gx  = c * 4;
    int off = (jq*4)*G3_ + gz0*1024 + gy*32 + gx;
    int ptb = row*34 + 2 + gx;
    u32 d0[4], d1[4], d2[4], d3[4];    // per-point dwords (unrolled below)
    if (BIN) {
      const u16* s0 = (const u16*)xsrc_ + b*SB_ + f*SF_ + off;
      const u16* s1 = s0 + 2048;       // plane zl+2
      uint2 a0={0,0},a1={0,0},a2={0,0},a3={0,0};
      uint2 e0={0,0},e1={0,0},e2={0,0},e3={0,0};
      if (gy >= 0) {
        if (gz0 >= 0) {
          a0 = *(const uint2*)(s0);
          a1 = *(const uint2*)(s0 + G3_);
          a2 = *(const uint2*)(s0 + 2*G3_);
          a3 = *(const uint2*)(s0 + 3*G3_);
        }
        e0 = *(const uint2*)(s1);
        e1 = *(const uint2*)(s1 + G3_);
        e2 = *(const uint2*)(s1 + 2*G3_);
        e3 = *(const uint2*)(s1 + 3*G3_);
      }
      // interleave: point px dword = (jlo[px], jhi[px]); lo16 = even comp
      d0[0] = __builtin_amdgcn_perm(a1.x, a0.x, 0x05040100u);
      d0[1] = __builtin_amdgcn_perm(a1.x, a0.x, 0x07060302u);
      d0[2] = __builtin_amdgcn_perm(a1.y, a0.y, 0x05040100u);
      d0[3] = __builtin_amdgcn_perm(a1.y, a0.y, 0x07060302u);
      d1[0] = __builtin_amdgcn_perm(a3.x, a2.x, 0x05040100u);
      d1[1] = __builtin_amdgcn_perm(a3.x, a2.x, 0x07060302u);
      d1[2] = __builtin_amdgcn_perm(a3.y, a2.y, 0x05040100u);
      d1[3] = __builtin_amdgcn_perm(a3.y, a2.y, 0x07060302u);
      d2[0] = __builtin_amdgcn_perm(e1.x, e0.x, 0x05040100u);
      d2[1] = __builtin_amdgcn_perm(e1.x, e0.x, 0x07060302u);
      d2[2] = __builtin_amdgcn_perm(e1.y, e0.y, 0x05040100u);
      d2[3] = __builtin_amdgcn_perm(e1.y, e0.y, 0x07060302u);
      d3[0] = __builtin_amdgcn_perm(e3.x, e2.x, 0x05040100u);
      d3[1] = __builtin_amdgcn_perm(e3.x, e2.x, 0x07060302u);
      d3[2] = __builtin_amdgcn_perm(e3.y, e2.y, 0x05040100u);
      d3[3] = __builtin_amdgcn_perm(e3.y, e2.y, 0x07060302u);
    } else {
      const float* s0 = (const float*)xsrc_ + b*SB_ + f*SF_ + off;
      const float* s1 = s0 + 2048;
      float4 A0={0,0,0,0},A1={0,0,0,0},A2={0,0,0,0},A3={0,0,0,0};
      float4 B0={0,0,0,0},B1={0,0,0,0},B2={0,0,0,0},B3={0,0,0,0};
      if (gy >= 0) {
        if (gz0 >= 0) {
          A0 = *(const float4*)(s0);
          A1 = *(const float4*)(s0 + G3_);
          A2 = *(const float4*)(s0 + 2*G3_);
          A3 = *(const float4*)(s0 + 3*G3_);
        }
        B0 = *(const float4*)(s1);
        B1 = *(const float4*)(s1 + G3_);
        B2 = *(const float4*)(s1 + 2*G3_);
        B3 = *(const float4*)(s1 + 3*G3_);
      }
      d0[0]=pk_bf16(A0.x,A1.x); d1[0]=pk_bf16(A2.x,A3.x);
      d2[0]=pk_bf16(B0.x,B1.x); d3[0]=pk_bf16(B2.x,B3.x);
      d0[1]=pk_bf16(A0.y,A1.y); d1[1]=pk_bf16(A2.y,A3.y);
      d2[1]=pk_bf16(B0.y,B1.y); d3[1]=pk_bf16(B2.y,B3.y);
      d0[2]=pk_bf16(A0.z,A1.z); d1[2]=pk_bf16(A2.z,A3.z);
      d2[2]=pk_bf16(B0.z,B1.z); d3[2]=pk_bf16(B2.z,B3.z);
      d0[3]=pk_bf16(A0.w,A1.w); d1[3]=pk_bf16(A2.w,A3.w);
      d2[3]=pk_bf16(B0.w,B1.w); d3[3]=pk_bf16(B2.w,B3.w);
    }
    #define STW(px) { \
      uint4 d; d.x = d0[px]; d.y = d1[px]; d.z = d2[px]; d.w = d3[px]; \
      int pt = ptb + px; \
      *(uint4*)&xk[pt*16 + ((qq ^ (pt & 3)) << 2)] = d; }
    STW(0) STW(1) STW(2) STW(3)
    #undef STW
  }

  // A fragments after staging (cuts peak VGPR pressure)
  short8v a[9];
  const u16* ap = Apack + (size_t)((p*8 + f) * 9) * 512;
  #pragma unroll
  for (int t = 0; t < 9; ++t)
    a[t] = *(const short8v*)(ap + (t*64 + lane)*8);

  __syncthreads();

  // ---- compute: wave wid owns y rows 2*wid..2*wid+1, both x halves ----
  const float* bb = biases + (f*P_ + p)*8;
  float bias[4];
  #pragma unroll
  for (int r = 0; r < 4; ++r) bias[r] = bb[(g & 1)*4 + r];
  int zoff = g >> 1;

  #pragma unroll
  for (int yi = 0; yi < 2; ++yi) {
    int yr = wid*2 + yi;
    f32x4 acc0 = {0.f,0.f,0.f,0.f}, acc1 = {0.f,0.f,0.f,0.f};
    #pragma unroll
    for (int dy = 0; dy < 3; ++dy) {
      int prow = (yr + dy)*34;
      #pragma unroll
      for (int dx = 0; dx < 3; ++dx) {
        int t = dy*3 + dx;
        int pt0 = prow + ln + dx;
        int dwb = pt0*16 + ((g ^ (pt0 & 3)) << 2);
        short8v b0 = *(const short8v*)&xk[dwb];
        short8v b1 = *(const short8v*)&xk[dwb + 256];   // pt0+16: same swizzle
        acc0 = __builtin_amdgcn_mfma_f32_16x16x32_bf16(a[t], b0, acc0, 0, 0, 0);
        acc1 = __builtin_amdgcn_mfma_f32_16x16x32_bf16(a[t], b1, acc1, 0, 0, 0);
      }
    }
    // D layout: col = lane&15 = x, row = 4g+r = (zoff*8 + i)
    u16* yb = y + b*SB_ + f*SF_ + (z0 + zoff)*1024 + (y0 + yr)*32 + ln;
    #pragma unroll
    for (int r = 0; r < 4; ++r) {
      int i = (g & 1)*4 + r;
      u16* ybi = yb + i*G3_;
      ybi[0]  = (u16)bf16_rne(fast_tanh(acc0[r] + bias[r]));
      ybi[16] = (u16)bf16_rne(fast_tanh(acc1[r] + bias[r]));
    }
  }
}

// ---------------------------------------------------------------------------
// cross-field mix + residual (bf16 in/out): 8 x-positions per thread.
// X[b,g,i,s] = a*xb + (1-a)*sum_f mix[g,f]*Y[b,f,i,s]
template<bool XBF>
__global__ void mix_kernel(const u16* __restrict__ ybuf,
                           const void* __restrict__ xbsrc_,
                           u16* __restrict__ xdst,
                           const float* __restrict__ mix,
                           const float* __restrict__ pal,
                           int p) {
  int tid = blockIdx.x * 256 + threadIdx.x;   // 524288 total
  int s8 = tid & 4095;            // G3/8
  int i  = (tid >> 12) & 7;
  int b  =  tid >> 15;
  int base = b*SB_ + i*G3_ + s8*8;
  float a  = fast_sig(pal[p]);
  float na = 1.f - a;

  float yv[8][8];
  #pragma unroll
  for (int ff = 0; ff < 8; ++ff) {
    uint4 u = *(const uint4*)(ybuf + base + ff*SF_);
    yv[ff][0]=bl(u.x); yv[ff][1]=bh(u.x); yv[ff][2]=bl(u.y); yv[ff][3]=bh(u.y);
    yv[ff][4]=bl(u.z); yv[ff][5]=bh(u.z); yv[ff][6]=bl(u.w); yv[ff][7]=bh(u.w);
  }

  #pragma unroll
  for (int g = 0; g < 8; ++g) {
    float xb[8];
    if (XBF) {
      uint4 u = *(const uint4*)((const u16*)xbsrc_ + base + g*SF_);
      xb[0]=bl(u.x); xb[1]=bh(u.x); xb[2]=bl(u.y); xb[3]=bh(u.y);
      xb[4]=bl(u.z); xb[5]=bh(u.z); xb[6]=bl(u.w); xb[7]=bh(u.w);
    } else {
      const float* s = (const float*)xbsrc_ + base + g*SF_;
      float4 f0 = *(const float4*)(s);
      float4 f1 = *(const float4*)(s + 4);
      xb[0]=f0.x; xb[1]=f0.y; xb[2]=f0.z; xb[3]=f0.w;
      xb[4]=f1.x; xb[5]=f1.y; xb[6]=f1.z; xb[7]=f1.w;
    }
    float o[8];
    #pragma unroll
    for (int e = 0; e < 8; ++e) o[e] = 0.f;
    #pragma unroll
    for (int ff = 0; ff < 8; ++ff) {
      float m = mix[(p*8 + g)*8 + ff];
      #pragma unroll
      for (int e = 0; e < 8; ++e) o[e] = fmaf(m, yv[ff][e], o[e]);
    }
    uint4 w;
    w.x = pk_bf16(a*xb[0] + na*o[0], a*xb[1] + na*o[1]);
    w.y = pk_bf16(a*xb[2] + na*o[2], a*xb[3] + na*o[3]);
    w.z = pk_bf16(a*xb[4] + na*o[4], a*xb[5] + na*o[5]);
    w.w = pk_bf16(a*xb[6] + na*o[6], a*xb[7] + na*o[7]);
    *(uint4*)(xdst + base + g*SF_) = w;
  }
}

// ---------------------------------------------------------------------------
// final pass mix fused with output gate (reads bf16 Y/Xb, f32 state; f32 out)
__global__ void mixgate_kernel(const u16* __restrict__ ybuf,
                               const u16* __restrict__ xbsrc,
                               const float* __restrict__ state,
                               float* __restrict__ out,
                               const float* __restrict__ mix,
                               const float* __restrict__ pal,
                               const float* __restrict__ gw,
                               const float* __restrict__ gb,
                               int p) {
  int tid = blockIdx.x * 256 + threadIdx.x;
  int s8 = tid & 4095;
  int i  = (tid >> 12) & 7;
  int b  =  tid >> 15;
  int base = b*SB_ + i*G3_ + s8*8;
  float a  = fast_sig(pal[p]);
  float na = 1.f - a;

  float yv[8][8];
  #pragma unroll
  for (int ff = 0; ff < 8; ++ff) {
    uint4 u = *(const uint4*)(ybuf + base + ff*SF_);
    yv[ff][0]=bl(u.x); yv[ff][1]=bh(u.x); yv[ff][2]=bl(u.y); yv[ff][3]=bh(u.y);
    yv[ff][4]=bl(u.z); yv[ff][5]=bh(u.z); yv[ff][6]=bl(u.w); yv[ff][7]=bh(u.w);
  }

  #pragma unroll
  for (int g = 0; g < 8; ++g) {
    float xb[8];
    {
      uint4 u = *(const uint4*)(xbsrc + base + g*SF_);
      xb[0]=bl(u.x); xb[1]=bh(u.x); xb[2]=bl(u.y); xb[3]=bh(u.y);
      xb[4]=bl(u.z); xb[5]=bh(u.z); xb[6]=bl(u.w); xb[7]=bh(u.w);
    }
    const float* sp = state + base + g*SF_;
    float4 s0 = *(const float4*)(sp);
    float4 s1 = *(const float4*)(sp + 4);
    float st[8] = {s0.x,s0.y,s0.z,s0.w, s1.x,s1.y,s1.z,s1.w};
    float o[8];
    #pragma unroll
    for (int e = 0; e < 8; ++e) o[e] = 0.f;
    #pragma unroll
    for (int ff = 0; ff < 8; ++ff) {
      float m = mix[(p*8 + g)*8 + ff];
      #pragma unroll
      for (int e = 0; e < 8; ++e) o[e] = fmaf(m, yv[ff][e], o[e]);
    }
    float w = gw[g*8 + i], bb = gb[g*8 + i];
    float r[8];
    #pragma unroll
    for (int e = 0; e < 8; ++e) {
      float xf = a*xb[e] + na*o[e];
      float gt = fast_sig(w*st[e] + bb);
      r[e] = gt*st[e] + (1.f - gt)*xf;
    }
    float* op = out + base + g*SF_;
    *(float4*)(op)     = make_float4(r[0],r[1],r[2],r[3]);
    *(float4*)(op + 4) = make_float4(r[4],r[5],r[6],r[7]);
  }
}

// ---------------------------------------------------------------------------
extern "C" void kernel_launch(void* const* d_in, const int* in_sizes, int n_in,
                              void* d_out, int out_size, void* d_ws, size_t ws_size,
                              hipStream_t stream) {
  (void)in_sizes; (void)n_in; (void)out_size; (void)ws_size;
  const float* state       = (const float*)d_in[0];
  const float* all_weights = (const float*)d_in[1];
  const float* all_biases  = (const float*)d_in[2];
  const float* mix_logits  = (const float*)d_in[3];
  const float* pal         = (const float*)d_in[4];
  const float* gw          = (const float*)d_in[5];
  const float* gb          = (const float*)d_in[6];
  float* out = (float*)d_out;

  // ws layout: X bf16 (N_) | Y bf16 (N_) | Apack (147456 u16) | mix (256 f32)
  u16* X     = (u16*)d_ws;
  u16* Yb    = X + N_;
  u16* Apack = Yb + N_;
  float* mixb = (float*)(Apack + APACK_SZ);

  prep_kernel<<<dim3(APACK_SZ/256), dim3(256), 0, stream>>>(
      all_weights, mix_logits, Apack, mixb);

  for (int p = 0; p < P_; ++p) {
    if (p == 0)
      conv_kernel<false><<<dim3(B_*F_*16*4), dim3(256), 0, stream>>>(
          (const void*)state, Yb, Apack, all_biases, p);
    else
      conv_kernel<true><<<dim3(B_*F_*16*4), dim3(256), 0, stream>>>(
          (const void*)X, Yb, Apack, all_biases, p);

    if (p == 0)
      mix_kernel<false><<<dim3(2048), dim3(256), 0, stream>>>(
          Yb, (const void*)state, X, mixb, pal, p);
    else if (p < P_ - 1)
      mix_kernel<true><<<dim3(2048), dim3(256), 0, stream>>>(
          Yb, (const void*)X, X, mixb, pal, p);
    else
      mixgate_kernel<<<dim3(2048), dim3(256), 0, stream>>>(
          Yb, X, state, out, mixb, pal, gw, gb, p);
  }
}

// Round 8
// 320.829 us; speedup vs baseline: 8.1722x; 1.2256x over previous
//
#include <hip/hip_runtime.h>
#include <math.h>

// Problem constants
#define B_  16
#define F_  8
#define C_  8
#define G_  32
#define G3_ 32768
#define P_  4
#define N_  (B_*F_*C_*G3_)
#define SF_ (C_*G3_)
#define SB_ (F_*SF_)
#define APACK_SZ (P_*F_*9*64*8)

typedef __attribute__((ext_vector_type(8))) short short8v;
typedef __attribute__((ext_vector_type(4))) float f32x4;
typedef unsigned short u16;
typedef unsigned int u32;

__device__ __constant__ int c_k[8][8] = {
  {0,1,2,3,4,5,6,7},
  {1,0,4,5,2,3,7,6},
  {2,4,0,6,1,7,3,5},
  {3,5,6,0,7,1,2,4},
  {4,2,1,7,0,6,5,3},
  {5,3,7,1,6,0,4,2},
  {6,7,3,2,5,4,0,1},
  {7,6,5,4,3,2,1,0}};
__device__ __constant__ float c_s[8][8] = {
  { 1, 1, 1, 1,-1,-1,-1,-1},
  { 1, 1, 1, 1,-1,-1,-1,-1},
  { 1,-1, 1, 1, 1, 1,-1, 1},
  { 1,-1,-1, 1,-1, 1, 1,-1},
  { 1,-1, 1, 1, 1, 1,-1, 1},
  { 1,-1,-1, 1,-1, 1, 1,-1},
  { 1, 1,-1, 1, 1,-1, 1, 1},
  { 1, 1,-1, 1, 1,-1, 1, 1}};

__device__ __forceinline__ float fast_tanh(float v) {
  float e = __expf(2.f * v);
  return 1.f - 2.f / (e + 1.f);
}
__device__ __forceinline__ float fast_sig(float v) {
  return 1.f / (1.f + __expf(-v));
}
__device__ __forceinline__ u32 bf16_rne(float v) {
  u32 u = __float_as_uint(v);
  return (u + 0x7FFFu + ((u >> 16) & 1u)) >> 16;
}
__device__ __forceinline__ u32 pk_bf16(float a, float b) {
  u32 d;
  asm("v_cvt_pk_bf16_f32 %0, %1, %2" : "=v"(d) : "v"(a), "v"(b));
  return d;
}
__device__ __forceinline__ float bl(u32 u) { return __uint_as_float(u << 16); }
__device__ __forceinline__ float bh(u32 u) { return __uint_as_float(u & 0xffff0000u); }
__device__ __forceinline__ float b16f(u16 v) { return __uint_as_float(((u32)v) << 16); }

// position swizzle: quad qq of point pt stored at (qq ^ HS(pt)); HS(pt+16)==HS(pt)
#define HS(pt) (((pt) + ((pt) >> 2)) & 3)

// ---------------------------------------------------------------------------
// prep: A fragments in per-lane MFMA layout + softmax mix (unchanged from R7)
__global__ void prep_kernel(const float* __restrict__ all_weights,
                            const float* __restrict__ mix_logits,
                            u16* __restrict__ Apack,
                            float* __restrict__ mix) {
  int idx = blockIdx.x * 256 + threadIdx.x;
  if (idx < APACK_SZ) {
    int e = idx & 7;
    int l = (idx >> 3) & 63;
    int rest = idx >> 9;
    int t = rest % 9;
    int fp = rest / 9;
    int f = fp & 7, p = fp >> 3;
    int g = l >> 4, m = l & 15;
    int zoff = m >> 3, i = m & 7;
    int kk = g*4 + (e & 3) + ((e >= 4) ? 16 : 0);
    int zl = kk >> 3, j = kk & 7;
    int dz = zl - zoff;
    float val = 0.f;
    if (dz >= 0 && dz <= 2)
      val = c_s[i][j] * all_weights[((f*P_ + p)*27 + (dz*9 + t))*8 + c_k[i][j]];
    Apack[idx] = (u16)bf16_rne(val);
  }
  if (blockIdx.x == 0 && threadIdx.x < P_*F_) {
    int p = threadIdx.x / F_, g = threadIdx.x % F_;
    const float* row = &mix_logits[(p*F_ + g)*F_];
    float mx = row[0];
    for (int f = 1; f < F_; ++f) mx = fmaxf(mx, row[f]);
    float e[F_]; float sum = 0.f;
    for (int f = 0; f < F_; ++f) { e[f] = __expf(row[f] - mx); sum += e[f]; }
    float inv = 1.f / sum;
    for (int f = 0; f < F_; ++f) mix[(p*F_ + g)*F_ + f] = e[f] * inv;
  }
}

// ---------------------------------------------------------------------------
// Fused conv+tanh+mix(+gate).  Block: (b, z-pair, y-tile of 4), ALL 8 fields.
// LDS: 204 points (6 rows x 34 x') x 16 dwords (32 k bf16), quad at qq^HS(pt).
// MODE 0: f32 in, bf16 out (pass 0); 1: bf16->bf16; 2: bf16 in, gate, f32 out.
#define RSTG 6
#define TPTS 204     // 6*34

template<int MODE>
__device__ __forceinline__ uint4 field_step(
    int f, const void* __restrict__ xsrc_, const u16* __restrict__ Apack,
    const float* __restrict__ biases, int p, int b, int z0, int y0,
    u32* xk, int tid, int lane, int wid, int g, int ln) {
  if (f) __syncthreads();       // prev field's LDS reads done before overwrite

  // ---- stage field f: 4 qq x 6 rows x 8 chunks of 4 x-points ----
  if (tid < 192) {
    int qq  = tid / 48;
    int r2  = tid - qq*48;
    int row = r2 >> 3;
    int c   = r2 & 7;
    int zl = qq >> 1, jq = qq & 1;
    int gz0 = z0 - 2 + zl;             // may be <0; gz0+2 always valid
    int gy  = y0 - 2 + row;            // may be <0
    int gx  = c * 4;
    int off = (jq*4)*G3_ + gz0*1024 + gy*32 + gx;
    int ptb = row*34 + 2 + gx;
    u32 d0[4], d1[4], d2[4], d3[4];
    if (MODE != 0) {
      const u16* s0 = (const u16*)xsrc_ + (size_t)b*SB_ + f*SF_ + off;
      const u16* s1 = s0 + 2048;
      uint2 a0={0,0},a1={0,0},a2={0,0},a3={0,0};
      uint2 e0={0,0},e1={0,0},e2={0,0},e3={0,0};
      if (gy >= 0) {
        if (gz0 >= 0) {
          a0 = *(const uint2*)(s0);
          a1 = *(const uint2*)(s0 + G3_);
          a2 = *(const uint2*)(s0 + 2*G3_);
          a3 = *(const uint2*)(s0 + 3*G3_);
        }
        e0 = *(const uint2*)(s1);
        e1 = *(const uint2*)(s1 + G3_);
        e2 = *(const uint2*)(s1 + 2*G3_);
        e3 = *(const uint2*)(s1 + 3*G3_);
      }
      d0[0] = __builtin_amdgcn_perm(a1.x, a0.x, 0x05040100u);
      d0[1] = __builtin_amdgcn_perm(a1.x, a0.x, 0x07060302u);
      d0[2] = __builtin_amdgcn_perm(a1.y, a0.y, 0x05040100u);
      d0[3] = __builtin_amdgcn_perm(a1.y, a0.y, 0x07060302u);
      d1[0] = __builtin_amdgcn_perm(a3.x, a2.x, 0x05040100u);
      d1[1] = __builtin_amdgcn_perm(a3.x, a2.x, 0x07060302u);
      d1[2] = __builtin_amdgcn_perm(a3.y, a2.y, 0x05040100u);
      d1[3] = __builtin_amdgcn_perm(a3.y, a2.y, 0x07060302u);
      d2[0] = __builtin_amdgcn_perm(e1.x, e0.x, 0x05040100u);
      d2[1] = __builtin_amdgcn_perm(e1.x, e0.x, 0x07060302u);
      d2[2] = __builtin_amdgcn_perm(e1.y, e0.y, 0x05040100u);
      d2[3] = __builtin_amdgcn_perm(e1.y, e0.y, 0x07060302u);
      d3[0] = __builtin_amdgcn_perm(e3.x, e2.x, 0x05040100u);
      d3[1] = __builtin_amdgcn_perm(e3.x, e2.x, 0x07060302u);
      d3[2] = __builtin_amdgcn_perm(e3.y, e2.y, 0x05040100u);
      d3[3] = __builtin_amdgcn_perm(e3.y, e2.y, 0x07060302u);
    } else {
      const float* s0 = (const float*)xsrc_ + (size_t)b*SB_ + f*SF_ + off;
      const float* s1 = s0 + 2048;
      float4 A0={0,0,0,0},A1={0,0,0,0},A2={0,0,0,0},A3={0,0,0,0};
      float4 B0={0,0,0,0},B1={0,0,0,0},B2={0,0,0,0},B3={0,0,0,0};
      if (gy >= 0) {
        if (gz0 >= 0) {
          A0 = *(const float4*)(s0);
          A1 = *(const float4*)(s0 + G3_);
          A2 = *(const float4*)(s0 + 2*G3_);
          A3 = *(const float4*)(s0 + 3*G3_);
        }
        B0 = *(const float4*)(s1);
        B1 = *(const float4*)(s1 + G3_);
        B2 = *(const float4*)(s1 + 2*G3_);
        B3 = *(const float4*)(s1 + 3*G3_);
      }
      d0[0]=pk_bf16(A0.x,A1.x); d1[0]=pk_bf16(A2.x,A3.x);
      d2[0]=pk_bf16(B0.x,B1.x); d3[0]=pk_bf16(B2.x,B3.x);
      d0[1]=pk_bf16(A0.y,A1.y); d1[1]=pk_bf16(A2.y,A3.y);
      d2[1]=pk_bf16(B0.y,B1.y); d3[1]=pk_bf16(B2.y,B3.y);
      d0[2]=pk_bf16(A0.z,A1.z); d1[2]=pk_bf16(A2.z,A3.z);
      d2[2]=pk_bf16(B0.z,B1.z); d3[2]=pk_bf16(B2.z,B3.z);
      d0[3]=pk_bf16(A0.w,A1.w); d1[3]=pk_bf16(A2.w,A3.w);
      d2[3]=pk_bf16(B0.w,B1.w); d3[3]=pk_bf16(B2.w,B3.w);
    }
    #define STW(px) { \
      uint4 d; d.x = d0[px]; d.y = d1[px]; d.z = d2[px]; d.w = d3[px]; \
      int pt = ptb + px; \
      *(uint4*)&xk[pt*16 + ((qq ^ HS(pt)) << 2)] = d; }
    STW(0) STW(1) STW(2) STW(3)
    #undef STW
  }

  // A fragments for this field (overlaps barrier wait)
  short8v a[9];
  const u16* ap = Apack + (size_t)((p*8 + f) * 9) * 512;
  #pragma unroll
  for (int t = 0; t < 9; ++t)
    a[t] = *(const short8v*)(ap + (t*64 + lane)*8);

  __syncthreads();

  // ---- compute: wave wid owns y row wid, both x halves ----
  f32x4 acc0 = {0.f,0.f,0.f,0.f}, acc1 = {0.f,0.f,0.f,0.f};
  #pragma unroll
  for (int dy = 0; dy < 3; ++dy) {
    int prow = (wid + dy)*34;
    #pragma unroll
    for (int dx = 0; dx < 3; ++dx) {
      int t = dy*3 + dx;
      int pt0 = prow + ln + dx;
      int dwb = pt0*16 + ((g ^ HS(pt0)) << 2);
      short8v b0 = *(const short8v*)&xk[dwb];
      short8v b1 = *(const short8v*)&xk[dwb + 256];   // pt0+16: HS invariant
      acc0 = __builtin_amdgcn_mfma_f32_16x16x32_bf16(a[t], b0, acc0, 0, 0, 0);
      acc1 = __builtin_amdgcn_mfma_f32_16x16x32_bf16(a[t], b1, acc1, 0, 0, 0);
    }
  }

  const float* bb = biases + (f*P_ + p)*8 + (g & 1)*4;
  float b0v = bb[0], b1v = bb[1], b2v = bb[2], b3v = bb[3];
  uint4 yp;
  yp.x = pk_bf16(fast_tanh(acc0[0] + b0v), fast_tanh(acc0[1] + b1v));
  yp.y = pk_bf16(fast_tanh(acc0[2] + b2v), fast_tanh(acc0[3] + b3v));
  yp.z = pk_bf16(fast_tanh(acc1[0] + b0v), fast_tanh(acc1[1] + b1v));
  yp.w = pk_bf16(fast_tanh(acc1[2] + b2v), fast_tanh(acc1[3] + b3v));
  return yp;
}

template<int MODE>
__global__ __launch_bounds__(256, 4)
void fused_kernel(const void* __restrict__ xsrc_,
                  void* __restrict__ xdst_,
                  const float* __restrict__ state,
                  const u16* __restrict__ Apack,
                  const float* __restrict__ biases,
                  const float* __restrict__ mixb,
                  const float* __restrict__ pal,
                  const float* __restrict__ gw,
                  const float* __restrict__ gb,
                  int p) {
  __shared__ __align__(16) u32 xk[TPTS * 16];   // 13056 B

  int bid = blockIdx.x;
  int yt = bid & 7;
  int zt = (bid >> 3) & 15;
  int b  =  bid >> 7;
  int z0 = zt * 2, y0 = yt * 4;
  int tid  = threadIdx.x;
  int lane = tid & 63;
  int wid  = tid >> 6;
  int g    = lane >> 4;
  int ln   = lane & 15;

  // zero x-halo points (x'=0,1): 6 rows x 2 pts x 16 dwords = 192
  if (tid < 192) {
    int pt = (tid >> 5) * 34 + ((tid >> 4) & 1);
    xk[pt*16 + (tid & 15)] = 0u;
  }

  uint4 yp0 = field_step<MODE>(0, xsrc_, Apack, biases, p, b, z0, y0, xk, tid, lane, wid, g, ln);
  uint4 yp1 = field_step<MODE>(1, xsrc_, Apack, biases, p, b, z0, y0, xk, tid, lane, wid, g, ln);
  uint4 yp2 = field_step<MODE>(2, xsrc_, Apack, biases, p, b, z0, y0, xk, tid, lane, wid, g, ln);
  uint4 yp3 = field_step<MODE>(3, xsrc_, Apack, biases, p, b, z0, y0, xk, tid, lane, wid, g, ln);
  uint4 yp4 = field_step<MODE>(4, xsrc_, Apack, biases, p, b, z0, y0, xk, tid, lane, wid, g, ln);
  uint4 yp5 = field_step<MODE>(5, xsrc_, Apack, biases, p, b, z0, y0, xk, tid, lane, wid, g, ln);
  uint4 yp6 = field_step<MODE>(6, xsrc_, Apack, biases, p, b, z0, y0, xk, tid, lane, wid, g, ln);
  uint4 yp7 = field_step<MODE>(7, xsrc_, Apack, biases, p, b, z0, y0, xk, tid, lane, wid, g, ln);

  // ---- epilogue: unpack y, 8x8 mix, residual (+gate) ----
  float yf[8][8];
  #define UNP(F, YPV) \
    yf[F][0]=bl(YPV.x); yf[F][1]=bh(YPV.x); yf[F][2]=bl(YPV.y); yf[F][3]=bh(YPV.y); \
    yf[F][4]=bl(YPV.z); yf[F][5]=bh(YPV.z); yf[F][6]=bl(YPV.w); yf[F][7]=bh(YPV.w);
  UNP(0,yp0) UNP(1,yp1) UNP(2,yp2) UNP(3,yp3)
  UNP(4,yp4) UNP(5,yp5) UNP(6,yp6) UNP(7,yp7)
  #undef UNP

  float alpha = fast_sig(pal[p]);
  float na = 1.f - alpha;
  int zoff = g >> 1;
  int i0 = (g & 1)*4;
  size_t ebase = (size_t)b*SB_ + (size_t)(z0 + zoff)*1024 + (size_t)(y0 + wid)*32 + ln;

  #pragma unroll
  for (int gg = 0; gg < 8; ++gg) {
    const float* mr = mixb + (p*8 + gg)*8;
    float o[8] = {0.f,0.f,0.f,0.f,0.f,0.f,0.f,0.f};
    #pragma unroll
    for (int f = 0; f < 8; ++f) {
      float m = mr[f];
      #pragma unroll
      for (int e = 0; e < 8; ++e) o[e] = fmaf(m, yf[f][e], o[e]);
    }
    size_t obase = ebase + (size_t)gg*SF_;
    #pragma unroll
    for (int e = 0; e < 8; ++e) {
      size_t idx = obase + (size_t)(i0 + (e & 3))*G3_ + (e >> 2)*16;
      float xbv;
      if (MODE == 0) xbv = ((const float*)xsrc_)[idx];
      else           xbv = b16f(((const u16*)xsrc_)[idx]);
      float xf = alpha*xbv + na*o[e];
      if (MODE == 2) {
        float st = state[idx];
        float w = gw[gg*8 + i0 + (e & 3)];
        float bbv = gb[gg*8 + i0 + (e & 3)];
        float gt = fast_sig(w*st + bbv);
        ((float*)xdst_)[idx] = gt*st + (1.f - gt)*xf;
      } else {
        ((u16*)xdst_)[idx] = (u16)bf16_rne(xf);
      }
    }
  }
}

// ---------------------------------------------------------------------------
extern "C" void kernel_launch(void* const* d_in, const int* in_sizes, int n_in,
                              void* d_out, int out_size, void* d_ws, size_t ws_size,
                              hipStream_t stream) {
  (void)in_sizes; (void)n_in; (void)out_size; (void)ws_size;
  const float* state       = (const float*)d_in[0];
  const float* all_weights = (const float*)d_in[1];
  const float* all_biases  = (const float*)d_in[2];
  const float* mix_logits  = (const float*)d_in[3];
  const float* pal         = (const float*)d_in[4];
  const float* gw          = (const float*)d_in[5];
  const float* gb          = (const float*)d_in[6];
  float* out = (float*)d_out;

  // ws: X0 bf16 (N_) | X1 bf16 (N_) | Apack | mix
  u16* X0 = (u16*)d_ws;
  u16* X1 = X0 + N_;
  u16* Apack = X1 + N_;
  float* mixb = (float*)(Apack + APACK_SZ);

  prep_kernel<<<dim3(APACK_SZ/256), dim3(256), 0, stream>>>(
      all_weights, mix_logits, Apack, mixb);

  dim3 grid(2048), blk(256);
  // p0: state(f32) -> X0 ; p1: X0 -> X1 ; p2: X1 -> X0 ; p3: X0 (+state) -> out
  fused_kernel<0><<<grid, blk, 0, stream>>>((const void*)state, (void*)X0, state,
      Apack, all_biases, mixb, pal, gw, gb, 0);
  fused_kernel<1><<<grid, blk, 0, stream>>>((const void*)X0, (void*)X1, state,
      Apack, all_biases, mixb, pal, gw, gb, 1);
  fused_kernel<1><<<grid, blk, 0, stream>>>((const void*)X1, (void*)X0, state,
      Apack, all_biases, mixb, pal, gw, gb, 2);
  fused_kernel<2><<<grid, blk, 0, stream>>>((const void*)X0, (void*)out, state,
      Apack, all_biases, mixb, pal, gw, gb, 3);
}